// Round 2
// baseline (1264.517 us; speedup 1.0000x reference)
//
#include <hip/hip_runtime.h>
#include <stdint.h>

#define N_NODES 50000
#define N_EDGES 1600000
#define N_FEAT 128

// ---------------- threefry2x32 (bit-exact, KAT-verified vs Random123) ----------

struct KeyPair { uint32_t a, b; };

__host__ __device__ constexpr inline uint32_t rotl32(uint32_t x, int r) {
  return (x << r) | (x >> (32 - r));
}

__host__ __device__ constexpr inline KeyPair threefry2x32(uint32_t k0, uint32_t k1,
                                                          uint32_t x0, uint32_t x1) {
  const uint32_t ks0 = k0, ks1 = k1, ks2 = k0 ^ k1 ^ 0x1BD11BDAu;
  x0 += ks0;
  x1 += ks1;
  const int rotA[4] = {13, 15, 26, 6};
  const int rotB[4] = {17, 29, 16, 24};
  const uint32_t ks[3] = {ks0, ks1, ks2};
  for (int i = 0; i < 5; ++i) {
    const int* rot = (i & 1) ? rotB : rotA;
    for (int j = 0; j < 4; ++j) {
      x0 += x1;
      x1 = rotl32(x1, rot[j]);
      x1 ^= x0;
    }
    x0 += ks[(i + 1) % 3];
    x1 += ks[(i + 2) % 3] + (uint32_t)(i + 1);
  }
  return {x0, x1};
}

// mask_key = fold_in(key(42), 7) = threefry2x32(key=(0,42), data=(0,7)); compile-time.
// (fold_in is unaffected by jax_threefry_partitionable.)
constexpr KeyPair MASK_KEY = threefry2x32(0u, 42u, 0u, 7u);

// Partitionable (counter-mode) random_bits, the modern-JAX default:
// element i -> threefry2x32(key, (hi32(i), lo32(i))); 32-bit output = b1 ^ b2.
__device__ inline bool edge_keep(uint32_t e) {
  KeyPair r = threefry2x32(MASK_KEY.a, MASK_KEY.b, 0u, e);
  uint32_t bits = r.a ^ r.b;
  float u = __uint_as_float((bits >> 9) | 0x3f800000u) - 1.0f;
  return u < 0.9f;  // 0.9f == float32(0.9) threshold used by bernoulli
}

// ---------------- pass 1: dropout (one thread per edge) ------------------------

__global__ void __launch_bounds__(256) dropout_kernel(const float* __restrict__ adj_vals,
                                                      float* __restrict__ vals_drop) {
  int e = blockIdx.x * blockDim.x + threadIdx.x;
  if (e >= N_EDGES) return;
  vals_drop[e] = edge_keep((uint32_t)e) ? adj_vals[e] / 0.9f : 0.0f;
}

// ---------------- pass 2: scatter SpMM (64 lanes per edge, 2 feats/lane) -------

__global__ void __launch_bounds__(256) scatter_kernel(const float* __restrict__ x,
                                                      const float* __restrict__ vals_drop,
                                                      const int* __restrict__ row,
                                                      const int* __restrict__ col,
                                                      float* __restrict__ out) {
  long long t = (long long)blockIdx.x * blockDim.x + threadIdx.x;
  int e = (int)(t >> 6);
  int lane = (int)(t & 63);
  if (e >= N_EDGES) return;
  float v = vals_drop[e];
  if (v == 0.0f) return;  // dropped edge: skip all atomics
  int c = col[e];
  int r = row[e];
  float2 xf = *(const float2*)(x + (long long)c * N_FEAT + lane * 2);
  float* dst = out + (long long)r * N_FEAT + lane * 2;
  atomicAdd(dst, v * xf.x);
  atomicAdd(dst + 1, v * xf.y);
}

// ---------------- fused fallback (no workspace needed) --------------------------

__global__ void __launch_bounds__(256) scatter_fused_kernel(const float* __restrict__ x,
                                                            const float* __restrict__ adj_vals,
                                                            const int* __restrict__ row,
                                                            const int* __restrict__ col,
                                                            float* __restrict__ out) {
  long long t = (long long)blockIdx.x * blockDim.x + threadIdx.x;
  int e = (int)(t >> 6);
  int lane = (int)(t & 63);
  if (e >= N_EDGES) return;
  if (!edge_keep((uint32_t)e)) return;
  float v = adj_vals[e] / 0.9f;
  int c = col[e];
  int r = row[e];
  float2 xf = *(const float2*)(x + (long long)c * N_FEAT + lane * 2);
  float* dst = out + (long long)r * N_FEAT + lane * 2;
  atomicAdd(dst, v * xf.x);
  atomicAdd(dst + 1, v * xf.y);
}

// ---------------- launch --------------------------------------------------------

extern "C" void kernel_launch(void* const* d_in, const int* in_sizes, int n_in,
                              void* d_out, int out_size, void* d_ws, size_t ws_size,
                              hipStream_t stream) {
  const float* x        = (const float*)d_in[0];
  const float* adj_vals = (const float*)d_in[1];
  const int*   row      = (const int*)d_in[2];
  const int*   col      = (const int*)d_in[3];
  float* out = (float*)d_out;

  // Harness poisons d_out with 0xAA before every launch; zero it (capture-safe).
  hipMemsetAsync(d_out, 0, (size_t)out_size * sizeof(float), stream);

  long long total_threads = (long long)N_EDGES * 64;
  int scatter_blocks = (int)((total_threads + 255) / 256);

  if (ws_size >= (size_t)N_EDGES * sizeof(float)) {
    float* vals_drop = (float*)d_ws;
    dropout_kernel<<<(N_EDGES + 255) / 256, 256, 0, stream>>>(adj_vals, vals_drop);
    scatter_kernel<<<scatter_blocks, 256, 0, stream>>>(x, vals_drop, row, col, out);
  } else {
    scatter_fused_kernel<<<scatter_blocks, 256, 0, stream>>>(x, adj_vals, row, col, out);
  }
}

// Round 3
// 462.238 us; speedup vs baseline: 2.7356x; 2.7356x over previous
//
#include <hip/hip_runtime.h>
#include <stdint.h>

#define N_NODES 50000
#define N_EDGES 1600000
#define N_FEAT 128

// ---------------- threefry2x32 (bit-exact, KAT-verified vs Random123) ----------

struct KeyPair { uint32_t a, b; };

__host__ __device__ constexpr inline uint32_t rotl32(uint32_t x, int r) {
  return (x << r) | (x >> (32 - r));
}

__host__ __device__ constexpr inline KeyPair threefry2x32(uint32_t k0, uint32_t k1,
                                                          uint32_t x0, uint32_t x1) {
  const uint32_t ks0 = k0, ks1 = k1, ks2 = k0 ^ k1 ^ 0x1BD11BDAu;
  x0 += ks0;
  x1 += ks1;
  const int rotA[4] = {13, 15, 26, 6};
  const int rotB[4] = {17, 29, 16, 24};
  const uint32_t ks[3] = {ks0, ks1, ks2};
  for (int i = 0; i < 5; ++i) {
    const int* rot = (i & 1) ? rotB : rotA;
    for (int j = 0; j < 4; ++j) {
      x0 += x1;
      x1 = rotl32(x1, rot[j]);
      x1 ^= x0;
    }
    x0 += ks[(i + 1) % 3];
    x1 += ks[(i + 2) % 3] + (uint32_t)(i + 1);
  }
  return {x0, x1};
}

// mask_key = fold_in(key(42), 7); compile-time. (fold_in unaffected by partitionable flag.)
constexpr KeyPair MASK_KEY = threefry2x32(0u, 42u, 0u, 7u);

// Partitionable (counter-mode) random_bits: element i -> threefry(key, (0, i)), bits = b1^b2.
__device__ inline bool edge_keep(uint32_t e) {
  KeyPair r = threefry2x32(MASK_KEY.a, MASK_KEY.b, 0u, e);
  uint32_t bits = r.a ^ r.b;
  float u = __uint_as_float((bits >> 9) | 0x3f800000u) - 1.0f;
  return u < 0.9f;
}

// ---------------- CSR build ----------------------------------------------------

// counts[r] += 1 for each kept edge
__global__ void __launch_bounds__(256) hist_kernel(const int* __restrict__ row,
                                                   uint32_t* __restrict__ counts) {
  int e = blockIdx.x * blockDim.x + threadIdx.x;
  if (e >= N_EDGES) return;
  if (!edge_keep((uint32_t)e)) return;
  atomicAdd(&counts[row[e]], 1u);
}

// single-workgroup exclusive scan: counts -> row_start (N+1) and row_cursor (N)
#define SCAN_T 1024
#define SCAN_CHUNK ((N_NODES + SCAN_T - 1) / SCAN_T)
__global__ void __launch_bounds__(SCAN_T) scan_kernel(const uint32_t* __restrict__ counts,
                                                      uint32_t* __restrict__ row_start,
                                                      uint32_t* __restrict__ row_cursor) {
  __shared__ uint32_t s[SCAN_T];
  int t = threadIdx.x;
  int lo = t * SCAN_CHUNK;
  int hi = min(lo + SCAN_CHUNK, N_NODES);
  uint32_t sum = 0;
  for (int i = lo; i < hi; ++i) sum += counts[i];
  s[t] = sum;
  __syncthreads();
  for (int off = 1; off < SCAN_T; off <<= 1) {
    uint32_t v = s[t];
    uint32_t u = (t >= off) ? s[t - off] : 0u;
    __syncthreads();
    s[t] = v + u;
    __syncthreads();
  }
  uint32_t base = s[t] - sum;  // exclusive prefix of this thread's chunk
  for (int i = lo; i < hi; ++i) {
    row_start[i] = base;
    row_cursor[i] = base;
    base += counts[i];
  }
  if (t == SCAN_T - 1) row_start[N_NODES] = s[SCAN_T - 1];
}

// scatter kept edges into CSR slots; payload = (col << 32) | bits(val)
__global__ void __launch_bounds__(256) bin_kernel(const float* __restrict__ adj_vals,
                                                  const int* __restrict__ row,
                                                  const int* __restrict__ col,
                                                  uint32_t* __restrict__ row_cursor,
                                                  uint64_t* __restrict__ payload) {
  int e = blockIdx.x * blockDim.x + threadIdx.x;
  if (e >= N_EDGES) return;
  if (!edge_keep((uint32_t)e)) return;
  float v = adj_vals[e] / 0.9f;
  uint32_t pos = atomicAdd(&row_cursor[row[e]], 1u);
  payload[pos] = ((uint64_t)(uint32_t)col[e] << 32) | (uint64_t)__float_as_uint(v);
}

// one 128-thread block per row; thread = feature; register accumulate, single write
__global__ void __launch_bounds__(128) gather_kernel(const float* __restrict__ x,
                                                     const uint64_t* __restrict__ payload,
                                                     const uint32_t* __restrict__ row_start,
                                                     float* __restrict__ out) {
  int r = blockIdx.x;
  int f = threadIdx.x;
  uint32_t s = row_start[r];
  uint32_t e = row_start[r + 1];
  float acc = 0.0f;
  uint32_t i = s;
  // 2-wide manual unroll for load ILP
  for (; i + 2 <= e; i += 2) {
    uint64_t p0 = payload[i];
    uint64_t p1 = payload[i + 1];
    int c0 = (int)(p0 >> 32);
    int c1 = (int)(p1 >> 32);
    float v0 = __uint_as_float((uint32_t)p0);
    float v1 = __uint_as_float((uint32_t)p1);
    float x0 = x[(size_t)c0 * N_FEAT + f];
    float x1 = x[(size_t)c1 * N_FEAT + f];
    acc += v0 * x0;
    acc += v1 * x1;
  }
  if (i < e) {
    uint64_t p0 = payload[i];
    int c0 = (int)(p0 >> 32);
    float v0 = __uint_as_float((uint32_t)p0);
    acc += v0 * x[(size_t)c0 * N_FEAT + f];
  }
  out[(size_t)r * N_FEAT + f] = acc;
}

// ---------------- fallback: fused atomic scatter (small ws) ---------------------

__global__ void __launch_bounds__(256) scatter_fused_kernel(const float* __restrict__ x,
                                                            const float* __restrict__ adj_vals,
                                                            const int* __restrict__ row,
                                                            const int* __restrict__ col,
                                                            float* __restrict__ out) {
  long long t = (long long)blockIdx.x * blockDim.x + threadIdx.x;
  int e = (int)(t >> 6);
  int lane = (int)(t & 63);
  if (e >= N_EDGES) return;
  if (!edge_keep((uint32_t)e)) return;
  float v = adj_vals[e] / 0.9f;
  int c = col[e];
  int r = row[e];
  float2 xf = *(const float2*)(x + (long long)c * N_FEAT + lane * 2);
  float* dst = out + (long long)r * N_FEAT + lane * 2;
  atomicAdd(dst, v * xf.x);
  atomicAdd(dst + 1, v * xf.y);
}

// ---------------- launch --------------------------------------------------------

extern "C" void kernel_launch(void* const* d_in, const int* in_sizes, int n_in,
                              void* d_out, int out_size, void* d_ws, size_t ws_size,
                              hipStream_t stream) {
  const float* x        = (const float*)d_in[0];
  const float* adj_vals = (const float*)d_in[1];
  const int*   row      = (const int*)d_in[2];
  const int*   col      = (const int*)d_in[3];
  float* out = (float*)d_out;

  // workspace layout (16B-aligned slabs)
  size_t off_counts  = 0;                                   // N u32 (also scan input)
  size_t off_start   = off_counts + ((size_t)N_NODES * 4 + 255 & ~255ull);  // N+1 u32
  size_t off_cursor  = off_start + (((size_t)(N_NODES + 1) * 4 + 255) & ~255ull);  // N u32
  size_t off_payload = off_cursor + (((size_t)N_NODES * 4 + 255) & ~255ull);       // E u64
  size_t ws_need = off_payload + (size_t)N_EDGES * 8;

  if (ws_size >= ws_need) {
    uint32_t* counts   = (uint32_t*)((char*)d_ws + off_counts);
    uint32_t* rstart   = (uint32_t*)((char*)d_ws + off_start);
    uint32_t* rcursor  = (uint32_t*)((char*)d_ws + off_cursor);
    uint64_t* payload  = (uint64_t*)((char*)d_ws + off_payload);

    hipMemsetAsync(counts, 0, (size_t)N_NODES * 4, stream);
    hist_kernel<<<(N_EDGES + 255) / 256, 256, 0, stream>>>(row, counts);
    scan_kernel<<<1, SCAN_T, 0, stream>>>(counts, rstart, rcursor);
    bin_kernel<<<(N_EDGES + 255) / 256, 256, 0, stream>>>(adj_vals, row, col, rcursor, payload);
    gather_kernel<<<N_NODES, 128, 0, stream>>>(x, payload, rstart, out);
  } else {
    hipMemsetAsync(d_out, 0, (size_t)out_size * sizeof(float), stream);
    long long total_threads = (long long)N_EDGES * 64;
    int scatter_blocks = (int)((total_threads + 255) / 256);
    scatter_fused_kernel<<<scatter_blocks, 256, 0, stream>>>(x, adj_vals, row, col, out);
  }
}

// Round 4
// 274.850 us; speedup vs baseline: 4.6008x; 1.6818x over previous
//
#include <hip/hip_runtime.h>
#include <stdint.h>

#define N_NODES 50000
#define N_EDGES 1600000
#define N_FEAT 128
#define CAP 64            // bucket slots per row; Poisson(28.8) mean, +6.5 sigma
#define OVF_CAP 4096      // overflow list capacity (expected usage: 0)

// ---------------- threefry2x32 (bit-exact, KAT-verified vs Random123) ----------

struct KeyPair { uint32_t a, b; };

__host__ __device__ constexpr inline uint32_t rotl32(uint32_t x, int r) {
  return (x << r) | (x >> (32 - r));
}

__host__ __device__ constexpr inline KeyPair threefry2x32(uint32_t k0, uint32_t k1,
                                                          uint32_t x0, uint32_t x1) {
  const uint32_t ks0 = k0, ks1 = k1, ks2 = k0 ^ k1 ^ 0x1BD11BDAu;
  x0 += ks0;
  x1 += ks1;
  const int rotA[4] = {13, 15, 26, 6};
  const int rotB[4] = {17, 29, 16, 24};
  const uint32_t ks[3] = {ks0, ks1, ks2};
  for (int i = 0; i < 5; ++i) {
    const int* rot = (i & 1) ? rotB : rotA;
    for (int j = 0; j < 4; ++j) {
      x0 += x1;
      x1 = rotl32(x1, rot[j]);
      x1 ^= x0;
    }
    x0 += ks[(i + 1) % 3];
    x1 += ks[(i + 2) % 3] + (uint32_t)(i + 1);
  }
  return {x0, x1};
}

// mask_key = fold_in(key(42), 7); compile-time.
constexpr KeyPair MASK_KEY = threefry2x32(0u, 42u, 0u, 7u);

// Partitionable (counter-mode) random_bits: element i -> threefry(key, (0, i)), bits = b1^b2.
__device__ inline bool edge_keep(uint32_t e) {
  KeyPair r = threefry2x32(MASK_KEY.a, MASK_KEY.b, 0u, e);
  uint32_t bits = r.a ^ r.b;
  float u = __uint_as_float((bits >> 9) | 0x3f800000u) - 1.0f;
  return u < 0.9f;
}

// =================== PRIMARY PATH: fixed-capacity buckets ======================

__global__ void __launch_bounds__(256) init_kernel(uint32_t* __restrict__ cursor,
                                                   uint32_t* __restrict__ ovf_count) {
  int i = blockIdx.x * blockDim.x + threadIdx.x;
  if (i < N_NODES) cursor[i] = (uint32_t)i * CAP;
  if (i == 0) *ovf_count = 0;
}

// one edge pass: keep-test, allocate bucket slot, write (col,val) payload
__global__ void __launch_bounds__(256) bin_bucket_kernel(const float* __restrict__ adj_vals,
                                                         const int* __restrict__ row,
                                                         const int* __restrict__ col,
                                                         uint32_t* __restrict__ cursor,
                                                         uint64_t* __restrict__ payload,
                                                         uint32_t* __restrict__ ovf_count,
                                                         uint32_t* __restrict__ ovf) {
  int e = blockIdx.x * blockDim.x + threadIdx.x;
  if (e >= N_EDGES) return;
  if (!edge_keep((uint32_t)e)) return;
  float v = adj_vals[e] / 0.9f;
  int r = row[e];
  uint32_t pos = atomicAdd(&cursor[r], 1u);
  if (pos < (uint32_t)r * CAP + CAP) {
    payload[pos] = ((uint64_t)(uint32_t)col[e] << 32) | (uint64_t)__float_as_uint(v);
  } else {
    uint32_t oi = atomicAdd(ovf_count, 1u);
    if (oi < OVF_CAP) ovf[oi] = (uint32_t)e;  // statistically never; exact if it happens
  }
}

// 32 lanes per row, float4 per lane (4 feats); 4 rows per 128-thread block
__global__ void __launch_bounds__(128) gather_bucket_kernel(const float* __restrict__ x,
                                                            const uint64_t* __restrict__ payload,
                                                            const uint32_t* __restrict__ cursor,
                                                            float* __restrict__ out) {
  int r = blockIdx.x * 4 + (threadIdx.x >> 5);
  int lane = threadIdx.x & 31;
  uint32_t base = (uint32_t)r * CAP;
  uint32_t end = cursor[r];
  uint32_t cap_end = base + CAP;
  if (end > cap_end) end = cap_end;
  const float4* x4 = (const float4*)x;
  float4 acc = make_float4(0.f, 0.f, 0.f, 0.f);
  uint32_t i = base;
  for (; i + 2 <= end; i += 2) {
    uint64_t p0 = payload[i];
    uint64_t p1 = payload[i + 1];
    int c0 = (int)(p0 >> 32);
    int c1 = (int)(p1 >> 32);
    float v0 = __uint_as_float((uint32_t)p0);
    float v1 = __uint_as_float((uint32_t)p1);
    float4 a0 = x4[(size_t)c0 * 32 + lane];
    float4 a1 = x4[(size_t)c1 * 32 + lane];
    acc.x += v0 * a0.x; acc.y += v0 * a0.y; acc.z += v0 * a0.z; acc.w += v0 * a0.w;
    acc.x += v1 * a1.x; acc.y += v1 * a1.y; acc.z += v1 * a1.z; acc.w += v1 * a1.w;
  }
  if (i < end) {
    uint64_t p0 = payload[i];
    int c0 = (int)(p0 >> 32);
    float v0 = __uint_as_float((uint32_t)p0);
    float4 a0 = x4[(size_t)c0 * 32 + lane];
    acc.x += v0 * a0.x; acc.y += v0 * a0.y; acc.z += v0 * a0.z; acc.w += v0 * a0.w;
  }
  ((float4*)out)[(size_t)r * 32 + lane] = acc;  // writes every row: no d_out memset needed
}

// after gather: atomically fold in any overflowed edges (expected: none)
__global__ void __launch_bounds__(256) ovf_kernel(const float* __restrict__ x,
                                                  const float* __restrict__ adj_vals,
                                                  const int* __restrict__ row,
                                                  const int* __restrict__ col,
                                                  const uint32_t* __restrict__ ovf_count,
                                                  const uint32_t* __restrict__ ovf,
                                                  float* __restrict__ out) {
  uint32_t n = *ovf_count;
  if (n > OVF_CAP) n = OVF_CAP;
  int g = (int)((blockIdx.x * blockDim.x + threadIdx.x) >> 7);   // group of 128 lanes
  int f = threadIdx.x & 127;
  const int ngroups = (64 * 256) >> 7;  // grid fixed at 64 blocks
  for (uint32_t oi = g; oi < n; oi += ngroups) {
    int e = (int)ovf[oi];
    float v = adj_vals[e] / 0.9f;
    int r = row[e];
    int c = col[e];
    atomicAdd(&out[(size_t)r * N_FEAT + f], v * x[(size_t)c * N_FEAT + f]);
  }
}

// =================== FALLBACK 1: exact CSR (R3 code) ===========================

__global__ void __launch_bounds__(256) hist_kernel(const int* __restrict__ row,
                                                   uint32_t* __restrict__ counts) {
  int e = blockIdx.x * blockDim.x + threadIdx.x;
  if (e >= N_EDGES) return;
  if (!edge_keep((uint32_t)e)) return;
  atomicAdd(&counts[row[e]], 1u);
}

#define SCAN_T 1024
#define SCAN_CHUNK ((N_NODES + SCAN_T - 1) / SCAN_T)
__global__ void __launch_bounds__(SCAN_T) scan_kernel(const uint32_t* __restrict__ counts,
                                                      uint32_t* __restrict__ row_start,
                                                      uint32_t* __restrict__ row_cursor) {
  __shared__ uint32_t s[SCAN_T];
  int t = threadIdx.x;
  int lo = t * SCAN_CHUNK;
  int hi = min(lo + SCAN_CHUNK, N_NODES);
  uint32_t sum = 0;
  for (int i = lo; i < hi; ++i) sum += counts[i];
  s[t] = sum;
  __syncthreads();
  for (int off = 1; off < SCAN_T; off <<= 1) {
    uint32_t v = s[t];
    uint32_t u = (t >= off) ? s[t - off] : 0u;
    __syncthreads();
    s[t] = v + u;
    __syncthreads();
  }
  uint32_t base = s[t] - sum;
  for (int i = lo; i < hi; ++i) {
    row_start[i] = base;
    row_cursor[i] = base;
    base += counts[i];
  }
  if (t == SCAN_T - 1) row_start[N_NODES] = s[SCAN_T - 1];
}

__global__ void __launch_bounds__(256) bin_kernel(const float* __restrict__ adj_vals,
                                                  const int* __restrict__ row,
                                                  const int* __restrict__ col,
                                                  uint32_t* __restrict__ row_cursor,
                                                  uint64_t* __restrict__ payload) {
  int e = blockIdx.x * blockDim.x + threadIdx.x;
  if (e >= N_EDGES) return;
  if (!edge_keep((uint32_t)e)) return;
  float v = adj_vals[e] / 0.9f;
  uint32_t pos = atomicAdd(&row_cursor[row[e]], 1u);
  payload[pos] = ((uint64_t)(uint32_t)col[e] << 32) | (uint64_t)__float_as_uint(v);
}

__global__ void __launch_bounds__(128) gather_kernel(const float* __restrict__ x,
                                                     const uint64_t* __restrict__ payload,
                                                     const uint32_t* __restrict__ row_start,
                                                     float* __restrict__ out) {
  int r = blockIdx.x;
  int f = threadIdx.x;
  uint32_t s = row_start[r];
  uint32_t e = row_start[r + 1];
  float acc = 0.0f;
  uint32_t i = s;
  for (; i + 2 <= e; i += 2) {
    uint64_t p0 = payload[i];
    uint64_t p1 = payload[i + 1];
    int c0 = (int)(p0 >> 32);
    int c1 = (int)(p1 >> 32);
    float v0 = __uint_as_float((uint32_t)p0);
    float v1 = __uint_as_float((uint32_t)p1);
    acc += v0 * x[(size_t)c0 * N_FEAT + f];
    acc += v1 * x[(size_t)c1 * N_FEAT + f];
  }
  if (i < e) {
    uint64_t p0 = payload[i];
    acc += __uint_as_float((uint32_t)p0) * x[(size_t)(p0 >> 32) * N_FEAT + f];
  }
  out[(size_t)r * N_FEAT + f] = acc;
}

// =================== FALLBACK 2: fused atomic scatter ==========================

__global__ void __launch_bounds__(256) scatter_fused_kernel(const float* __restrict__ x,
                                                            const float* __restrict__ adj_vals,
                                                            const int* __restrict__ row,
                                                            const int* __restrict__ col,
                                                            float* __restrict__ out) {
  long long t = (long long)blockIdx.x * blockDim.x + threadIdx.x;
  int e = (int)(t >> 6);
  int lane = (int)(t & 63);
  if (e >= N_EDGES) return;
  if (!edge_keep((uint32_t)e)) return;
  float v = adj_vals[e] / 0.9f;
  float2 xf = *(const float2*)(x + (long long)col[e] * N_FEAT + lane * 2);
  float* dst = out + (long long)row[e] * N_FEAT + lane * 2;
  atomicAdd(dst, v * xf.x);
  atomicAdd(dst + 1, v * xf.y);
}

// ---------------- launch --------------------------------------------------------

extern "C" void kernel_launch(void* const* d_in, const int* in_sizes, int n_in,
                              void* d_out, int out_size, void* d_ws, size_t ws_size,
                              hipStream_t stream) {
  const float* x        = (const float*)d_in[0];
  const float* adj_vals = (const float*)d_in[1];
  const int*   row      = (const int*)d_in[2];
  const int*   col      = (const int*)d_in[3];
  float* out = (float*)d_out;

  // ---- bucket-path workspace layout ----
  size_t b_cursor  = 0;                                           // N u32
  size_t b_ovfc    = (b_cursor + (size_t)N_NODES * 4 + 255) & ~255ull;   // 1 u32
  size_t b_ovf     = (b_ovfc + 4 + 255) & ~255ull;                // OVF_CAP u32
  size_t b_payload = (b_ovf + (size_t)OVF_CAP * 4 + 255) & ~255ull;  // N*CAP u64
  size_t bucket_need = b_payload + (size_t)N_NODES * CAP * 8;

  // ---- CSR-path workspace layout ----
  size_t c_counts  = 0;
  size_t c_start   = (c_counts + (size_t)N_NODES * 4 + 255) & ~255ull;
  size_t c_cursor  = (c_start + (size_t)(N_NODES + 1) * 4 + 255) & ~255ull;
  size_t c_payload = (c_cursor + (size_t)N_NODES * 4 + 255) & ~255ull;
  size_t csr_need  = c_payload + (size_t)N_EDGES * 8;

  if (ws_size >= bucket_need) {
    uint32_t* cursor    = (uint32_t*)((char*)d_ws + b_cursor);
    uint32_t* ovf_count = (uint32_t*)((char*)d_ws + b_ovfc);
    uint32_t* ovf       = (uint32_t*)((char*)d_ws + b_ovf);
    uint64_t* payload   = (uint64_t*)((char*)d_ws + b_payload);

    init_kernel<<<(N_NODES + 255) / 256, 256, 0, stream>>>(cursor, ovf_count);
    bin_bucket_kernel<<<(N_EDGES + 255) / 256, 256, 0, stream>>>(
        adj_vals, row, col, cursor, payload, ovf_count, ovf);
    gather_bucket_kernel<<<N_NODES / 4, 128, 0, stream>>>(x, payload, cursor, out);
    ovf_kernel<<<64, 256, 0, stream>>>(x, adj_vals, row, col, ovf_count, ovf, out);
  } else if (ws_size >= csr_need) {
    uint32_t* counts  = (uint32_t*)((char*)d_ws + c_counts);
    uint32_t* rstart  = (uint32_t*)((char*)d_ws + c_start);
    uint32_t* rcursor = (uint32_t*)((char*)d_ws + c_cursor);
    uint64_t* payload = (uint64_t*)((char*)d_ws + c_payload);

    hipMemsetAsync(counts, 0, (size_t)N_NODES * 4, stream);
    hist_kernel<<<(N_EDGES + 255) / 256, 256, 0, stream>>>(row, counts);
    scan_kernel<<<1, SCAN_T, 0, stream>>>(counts, rstart, rcursor);
    bin_kernel<<<(N_EDGES + 255) / 256, 256, 0, stream>>>(adj_vals, row, col, rcursor, payload);
    gather_kernel<<<N_NODES, 128, 0, stream>>>(x, payload, rstart, out);
  } else {
    hipMemsetAsync(d_out, 0, (size_t)out_size * sizeof(float), stream);
    long long total_threads = (long long)N_EDGES * 64;
    scatter_fused_kernel<<<(int)((total_threads + 255) / 256), 256, 0, stream>>>(
        x, adj_vals, row, col, out);
  }
}

// Round 5
// 254.443 us; speedup vs baseline: 4.9697x; 1.0802x over previous
//
#include <hip/hip_runtime.h>
#include <stdint.h>

#define N_NODES 50000
#define N_EDGES 1600000
#define N_FEAT 128
#define CAP 64            // final bucket slots per row; Poisson(28.8) mean, +6.5 sigma
#define OVF_CAP 65536     // overflow list capacity (expected usage: ~0)

// radix-partition parameters
#define NB 98             // coarse buckets = ceil(50000 / 512)
#define RSHIFT 9          // 512 rows per coarse bucket
#define NWG_A 256         // pass-A workgroups (one segment set each)
#define CAPW 88           // slots per (bucket, wg) segment; mean 57.6, +4 sigma
#define EPW (N_EDGES / NWG_A)  // 6250 edges per pass-A workgroup

// ---------------- threefry2x32 (bit-exact, KAT-verified vs Random123) ----------

struct KeyPair { uint32_t a, b; };

__host__ __device__ constexpr inline uint32_t rotl32(uint32_t x, int r) {
  return (x << r) | (x >> (32 - r));
}

__host__ __device__ constexpr inline KeyPair threefry2x32(uint32_t k0, uint32_t k1,
                                                          uint32_t x0, uint32_t x1) {
  const uint32_t ks0 = k0, ks1 = k1, ks2 = k0 ^ k1 ^ 0x1BD11BDAu;
  x0 += ks0;
  x1 += ks1;
  const int rotA[4] = {13, 15, 26, 6};
  const int rotB[4] = {17, 29, 16, 24};
  const uint32_t ks[3] = {ks0, ks1, ks2};
  for (int i = 0; i < 5; ++i) {
    const int* rot = (i & 1) ? rotB : rotA;
    for (int j = 0; j < 4; ++j) {
      x0 += x1;
      x1 = rotl32(x1, rot[j]);
      x1 ^= x0;
    }
    x0 += ks[(i + 1) % 3];
    x1 += ks[(i + 2) % 3] + (uint32_t)(i + 1);
  }
  return {x0, x1};
}

// mask_key = fold_in(key(42), 7); compile-time.
constexpr KeyPair MASK_KEY = threefry2x32(0u, 42u, 0u, 7u);

// Partitionable (counter-mode) random_bits: element i -> threefry(key, (0, i)), bits = b1^b2.
__device__ inline bool edge_keep(uint32_t e) {
  KeyPair r = threefry2x32(MASK_KEY.a, MASK_KEY.b, 0u, e);
  uint32_t bits = r.a ^ r.b;
  float u = __uint_as_float((bits >> 9) | 0x3f800000u) - 1.0f;
  return u < 0.9f;
}

// =================== PRIMARY PATH: two-pass radix partition ====================
// pack: (row << 48) | (col << 32) | f32bits(val)   [row, col < 65536]

// Pass A: per-workgroup private compaction into (bucket, wg) segments.
// All writes to a segment come from ONE CU contiguously -> lines merge -> dense writeback.
__global__ void __launch_bounds__(256) partA_kernel(const float* __restrict__ adj_vals,
                                                    const int* __restrict__ row,
                                                    const int* __restrict__ col,
                                                    uint64_t* __restrict__ coarse,
                                                    uint32_t* __restrict__ lens,
                                                    uint32_t* __restrict__ ovf_count,
                                                    uint64_t* __restrict__ ovf) {
  __shared__ uint32_t cnt[NB];
  int wg = blockIdx.x;
  int tid = threadIdx.x;
  if (tid < NB) cnt[tid] = 0;
  __syncthreads();
  int e0 = wg * EPW;
  int e1 = e0 + EPW;
  for (int e = e0 + tid; e < e1; e += 256) {
    if (!edge_keep((uint32_t)e)) continue;
    float v = adj_vals[e] / 0.9f;
    uint32_t r = (uint32_t)row[e];
    uint32_t c = (uint32_t)col[e];
    uint32_t b = r >> RSHIFT;
    uint32_t li = atomicAdd(&cnt[b], 1u);
    uint64_t p = ((uint64_t)r << 48) | ((uint64_t)c << 32) | (uint64_t)__float_as_uint(v);
    if (li < CAPW) {
      coarse[((size_t)b * NWG_A + wg) * CAPW + li] = p;
    } else {
      uint32_t oi = atomicAdd(ovf_count, 1u);
      if (oi < OVF_CAP) ovf[oi] = p;
    }
  }
  __syncthreads();
  if (tid < NB) lens[(size_t)tid * NWG_A + wg] = min(cnt[tid], (uint32_t)CAPW);
}

// Pass B: one workgroup per coarse bucket. Scan segment lengths, flattened sweep,
// scatter into final per-row slots. Destination = 256 KB contiguous -> L2-resident
// for the whole kernel -> merged dense writebacks. Per-row counts in LDS.
__global__ void __launch_bounds__(256) partB_kernel(const uint64_t* __restrict__ coarse,
                                                    const uint32_t* __restrict__ lens,
                                                    uint64_t* __restrict__ payload,
                                                    uint32_t* __restrict__ cursor,
                                                    uint32_t* __restrict__ ovf_count,
                                                    uint64_t* __restrict__ ovf) {
  int b = blockIdx.x;
  int tid = threadIdx.x;
  __shared__ uint32_t s[NWG_A];    // inclusive scan of segment lengths
  __shared__ uint32_t cnt[512];    // per local-row fill count
  uint32_t len = lens[(size_t)b * NWG_A + tid];
  s[tid] = len;
  cnt[tid] = 0;
  cnt[tid + 256] = 0;
  __syncthreads();
  for (int off = 1; off < NWG_A; off <<= 1) {
    uint32_t v = s[tid];
    uint32_t u = (tid >= off) ? s[tid - off] : 0u;
    __syncthreads();
    s[tid] = v + u;
    __syncthreads();
  }
  uint32_t total = s[NWG_A - 1];
  for (uint32_t t = tid; t < total; t += 256) {
    int lo = 0, hi = NWG_A - 1;
    while (lo < hi) {  // smallest seg with inclusive_prefix > t
      int mid = (lo + hi) >> 1;
      if (s[mid] > t) hi = mid; else lo = mid + 1;
    }
    uint32_t prev = lo ? s[lo - 1] : 0u;
    uint64_t p = coarse[((size_t)b * NWG_A + lo) * CAPW + (t - prev)];
    uint32_t r = (uint32_t)(p >> 48);
    uint32_t rl = r - ((uint32_t)b << RSHIFT);
    uint32_t idx = atomicAdd(&cnt[rl], 1u);
    if (idx < CAP) {
      payload[(size_t)r * CAP + idx] = p & 0x0000FFFFFFFFFFFFull;  // (col<<32)|val
    } else {
      uint32_t oi = atomicAdd(ovf_count, 1u);
      if (oi < OVF_CAP) ovf[oi] = p;
    }
  }
  __syncthreads();
  for (int k = tid; k < 512; k += 256) {
    uint32_t r = ((uint32_t)b << RSHIFT) + (uint32_t)k;
    if (r < N_NODES) cursor[r] = r * CAP + min(cnt[k], (uint32_t)CAP);
  }
}

// 32 lanes per row, float4 per lane (4 feats); 4 rows per 128-thread block
__global__ void __launch_bounds__(128) gather_bucket_kernel(const float* __restrict__ x,
                                                            const uint64_t* __restrict__ payload,
                                                            const uint32_t* __restrict__ cursor,
                                                            float* __restrict__ out) {
  int r = blockIdx.x * 4 + (threadIdx.x >> 5);
  int lane = threadIdx.x & 31;
  uint32_t base = (uint32_t)r * CAP;
  uint32_t end = cursor[r];
  uint32_t cap_end = base + CAP;
  if (end > cap_end) end = cap_end;
  const float4* x4 = (const float4*)x;
  float4 acc = make_float4(0.f, 0.f, 0.f, 0.f);
  uint32_t i = base;
  for (; i + 2 <= end; i += 2) {
    uint64_t p0 = payload[i];
    uint64_t p1 = payload[i + 1];
    int c0 = (int)(p0 >> 32);
    int c1 = (int)(p1 >> 32);
    float v0 = __uint_as_float((uint32_t)p0);
    float v1 = __uint_as_float((uint32_t)p1);
    float4 a0 = x4[(size_t)c0 * 32 + lane];
    float4 a1 = x4[(size_t)c1 * 32 + lane];
    acc.x += v0 * a0.x; acc.y += v0 * a0.y; acc.z += v0 * a0.z; acc.w += v0 * a0.w;
    acc.x += v1 * a1.x; acc.y += v1 * a1.y; acc.z += v1 * a1.z; acc.w += v1 * a1.w;
  }
  if (i < end) {
    uint64_t p0 = payload[i];
    int c0 = (int)(p0 >> 32);
    float v0 = __uint_as_float((uint32_t)p0);
    float4 a0 = x4[(size_t)c0 * 32 + lane];
    acc.x += v0 * a0.x; acc.y += v0 * a0.y; acc.z += v0 * a0.z; acc.w += v0 * a0.w;
  }
  ((float4*)out)[(size_t)r * 32 + lane] = acc;  // writes every row: no d_out memset
}

// exact cleanup for packed (row,col,val) overflow entries (expected: none)
__global__ void __launch_bounds__(256) ovf_pack_kernel(const float* __restrict__ x,
                                                       const uint32_t* __restrict__ ovf_count,
                                                       const uint64_t* __restrict__ ovf,
                                                       float* __restrict__ out) {
  uint32_t n = *ovf_count;
  if (n > OVF_CAP) n = OVF_CAP;
  int g = (int)((blockIdx.x * blockDim.x + threadIdx.x) >> 7);
  int f = threadIdx.x & 127;
  const int ngroups = (64 * 256) >> 7;
  for (uint32_t oi = g; oi < n; oi += ngroups) {
    uint64_t p = ovf[oi];
    uint32_t r = (uint32_t)(p >> 48);
    uint32_t c = (uint32_t)((p >> 32) & 0xFFFFu);
    float v = __uint_as_float((uint32_t)p);
    atomicAdd(&out[(size_t)r * N_FEAT + f], v * x[(size_t)c * N_FEAT + f]);
  }
}

// =================== FALLBACK 1: R4 direct-scatter buckets =====================

__global__ void __launch_bounds__(256) init_kernel(uint32_t* __restrict__ cursor,
                                                   uint32_t* __restrict__ ovf_count) {
  int i = blockIdx.x * blockDim.x + threadIdx.x;
  if (i < N_NODES) cursor[i] = (uint32_t)i * CAP;
  if (i == 0) *ovf_count = 0;
}

__global__ void __launch_bounds__(256) bin_bucket_kernel(const float* __restrict__ adj_vals,
                                                         const int* __restrict__ row,
                                                         const int* __restrict__ col,
                                                         uint32_t* __restrict__ cursor,
                                                         uint64_t* __restrict__ payload,
                                                         uint32_t* __restrict__ ovf_count,
                                                         uint32_t* __restrict__ ovf) {
  int e = blockIdx.x * blockDim.x + threadIdx.x;
  if (e >= N_EDGES) return;
  if (!edge_keep((uint32_t)e)) return;
  float v = adj_vals[e] / 0.9f;
  int r = row[e];
  uint32_t pos = atomicAdd(&cursor[r], 1u);
  if (pos < (uint32_t)r * CAP + CAP) {
    payload[pos] = ((uint64_t)(uint32_t)col[e] << 32) | (uint64_t)__float_as_uint(v);
  } else {
    uint32_t oi = atomicAdd(ovf_count, 1u);
    if (oi < OVF_CAP) ovf[oi] = (uint32_t)e;
  }
}

__global__ void __launch_bounds__(256) ovf_edge_kernel(const float* __restrict__ x,
                                                       const float* __restrict__ adj_vals,
                                                       const int* __restrict__ row,
                                                       const int* __restrict__ col,
                                                       const uint32_t* __restrict__ ovf_count,
                                                       const uint32_t* __restrict__ ovf,
                                                       float* __restrict__ out) {
  uint32_t n = *ovf_count;
  if (n > OVF_CAP) n = OVF_CAP;
  int g = (int)((blockIdx.x * blockDim.x + threadIdx.x) >> 7);
  int f = threadIdx.x & 127;
  const int ngroups = (64 * 256) >> 7;
  for (uint32_t oi = g; oi < n; oi += ngroups) {
    int e = (int)ovf[oi];
    float v = adj_vals[e] / 0.9f;
    atomicAdd(&out[(size_t)row[e] * N_FEAT + f], v * x[(size_t)col[e] * N_FEAT + f]);
  }
}

// =================== FALLBACK 2: fused atomic scatter ==========================

__global__ void __launch_bounds__(256) scatter_fused_kernel(const float* __restrict__ x,
                                                            const float* __restrict__ adj_vals,
                                                            const int* __restrict__ row,
                                                            const int* __restrict__ col,
                                                            float* __restrict__ out) {
  long long t = (long long)blockIdx.x * blockDim.x + threadIdx.x;
  int e = (int)(t >> 6);
  int lane = (int)(t & 63);
  if (e >= N_EDGES) return;
  if (!edge_keep((uint32_t)e)) return;
  float v = adj_vals[e] / 0.9f;
  float2 xf = *(const float2*)(x + (long long)col[e] * N_FEAT + lane * 2);
  float* dst = out + (long long)row[e] * N_FEAT + lane * 2;
  atomicAdd(dst, v * xf.x);
  atomicAdd(dst + 1, v * xf.y);
}

// ---------------- launch --------------------------------------------------------

extern "C" void kernel_launch(void* const* d_in, const int* in_sizes, int n_in,
                              void* d_out, int out_size, void* d_ws, size_t ws_size,
                              hipStream_t stream) {
  const float* x        = (const float*)d_in[0];
  const float* adj_vals = (const float*)d_in[1];
  const int*   row      = (const int*)d_in[2];
  const int*   col      = (const int*)d_in[3];
  float* out = (float*)d_out;

  // ---- radix-path workspace layout ----
  size_t a_cursor  = 0;                                                  // N u32
  size_t a_ovfc    = (a_cursor + (size_t)N_NODES * 4 + 255) & ~255ull;   // 1 u32
  size_t a_ovf     = (a_ovfc + 4 + 255) & ~255ull;                       // OVF_CAP u64
  size_t a_lens    = (a_ovf + (size_t)OVF_CAP * 8 + 255) & ~255ull;      // NB*NWG_A u32
  size_t a_coarse  = (a_lens + (size_t)NB * NWG_A * 4 + 255) & ~255ull;  // NB*NWG_A*CAPW u64
  size_t a_payload = (a_coarse + (size_t)NB * NWG_A * CAPW * 8 + 255) & ~255ull;  // N*CAP u64
  size_t radix_need = a_payload + (size_t)N_NODES * CAP * 8;

  // ---- R4 bucket-path workspace layout ----
  size_t b_cursor  = 0;
  size_t b_ovfc    = (b_cursor + (size_t)N_NODES * 4 + 255) & ~255ull;
  size_t b_ovf     = (b_ovfc + 4 + 255) & ~255ull;
  size_t b_payload = (b_ovf + (size_t)OVF_CAP * 4 + 255) & ~255ull;
  size_t bucket_need = b_payload + (size_t)N_NODES * CAP * 8;

  if (ws_size >= radix_need) {
    uint32_t* cursor    = (uint32_t*)((char*)d_ws + a_cursor);
    uint32_t* ovf_count = (uint32_t*)((char*)d_ws + a_ovfc);
    uint64_t* ovf       = (uint64_t*)((char*)d_ws + a_ovf);
    uint32_t* lens      = (uint32_t*)((char*)d_ws + a_lens);
    uint64_t* coarse    = (uint64_t*)((char*)d_ws + a_coarse);
    uint64_t* payload   = (uint64_t*)((char*)d_ws + a_payload);

    hipMemsetAsync(ovf_count, 0, 4, stream);
    partA_kernel<<<NWG_A, 256, 0, stream>>>(adj_vals, row, col, coarse, lens, ovf_count, ovf);
    partB_kernel<<<NB, 256, 0, stream>>>(coarse, lens, payload, cursor, ovf_count, ovf);
    gather_bucket_kernel<<<N_NODES / 4, 128, 0, stream>>>(x, payload, cursor, out);
    ovf_pack_kernel<<<64, 256, 0, stream>>>(x, ovf_count, ovf, out);
  } else if (ws_size >= bucket_need) {
    uint32_t* cursor    = (uint32_t*)((char*)d_ws + b_cursor);
    uint32_t* ovf_count = (uint32_t*)((char*)d_ws + b_ovfc);
    uint32_t* ovf       = (uint32_t*)((char*)d_ws + b_ovf);
    uint64_t* payload   = (uint64_t*)((char*)d_ws + b_payload);

    init_kernel<<<(N_NODES + 255) / 256, 256, 0, stream>>>(cursor, ovf_count);
    bin_bucket_kernel<<<(N_EDGES + 255) / 256, 256, 0, stream>>>(
        adj_vals, row, col, cursor, payload, ovf_count, ovf);
    gather_bucket_kernel<<<N_NODES / 4, 128, 0, stream>>>(x, payload, cursor, out);
    ovf_edge_kernel<<<64, 256, 0, stream>>>(x, adj_vals, row, col, ovf_count, ovf, out);
  } else {
    hipMemsetAsync(d_out, 0, (size_t)out_size * sizeof(float), stream);
    long long total_threads = (long long)N_EDGES * 64;
    scatter_fused_kernel<<<(int)((total_threads + 255) / 256), 256, 0, stream>>>(
        x, adj_vals, row, col, out);
  }
}

// Round 6
// 218.347 us; speedup vs baseline: 5.7913x; 1.1653x over previous
//
#include <hip/hip_runtime.h>
#include <stdint.h>

#define N_NODES 50000
#define N_EDGES 1600000
#define N_FEAT 128
#define CAP 64            // final bucket slots per row; Poisson(28.8) mean, +6.5 sigma
#define OVF_CAP 65536     // overflow list capacity (expected usage: ~0)

// radix-partition parameters
#define NB 98             // coarse buckets = ceil(50000 / 512)
#define RSHIFT 9          // 512 rows per coarse bucket
#define NWG_A 256         // pass-A workgroups (one segment set each)
#define CAPW 88           // slots per (bucket, wg) segment; mean 57.6, +4 sigma
#define EPW (N_EDGES / NWG_A)  // 6250 edges per pass-A workgroup

// ---------------- threefry2x32 (bit-exact, KAT-verified vs Random123) ----------

struct KeyPair { uint32_t a, b; };

__host__ __device__ constexpr inline uint32_t rotl32(uint32_t x, int r) {
  return (x << r) | (x >> (32 - r));
}

__host__ __device__ constexpr inline KeyPair threefry2x32(uint32_t k0, uint32_t k1,
                                                          uint32_t x0, uint32_t x1) {
  const uint32_t ks0 = k0, ks1 = k1, ks2 = k0 ^ k1 ^ 0x1BD11BDAu;
  x0 += ks0;
  x1 += ks1;
  const int rotA[4] = {13, 15, 26, 6};
  const int rotB[4] = {17, 29, 16, 24};
  const uint32_t ks[3] = {ks0, ks1, ks2};
  for (int i = 0; i < 5; ++i) {
    const int* rot = (i & 1) ? rotB : rotA;
    for (int j = 0; j < 4; ++j) {
      x0 += x1;
      x1 = rotl32(x1, rot[j]);
      x1 ^= x0;
    }
    x0 += ks[(i + 1) % 3];
    x1 += ks[(i + 2) % 3] + (uint32_t)(i + 1);
  }
  return {x0, x1};
}

// mask_key = fold_in(key(42), 7); compile-time.
constexpr KeyPair MASK_KEY = threefry2x32(0u, 42u, 0u, 7u);

// Partitionable (counter-mode) random_bits: element i -> threefry(key, (0, i)), bits = b1^b2.
__device__ inline bool edge_keep(uint32_t e) {
  KeyPair r = threefry2x32(MASK_KEY.a, MASK_KEY.b, 0u, e);
  uint32_t bits = r.a ^ r.b;
  float u = __uint_as_float((bits >> 9) | 0x3f800000u) - 1.0f;
  return u < 0.9f;
}

// =================== PRIMARY PATH: two-pass radix partition ====================
// pack: (row << 48) | (col << 32) | f32bits(val)   [row, col < 65536]

// Pass A: per-workgroup private compaction into (bucket, wg) segments.
__global__ void __launch_bounds__(256) partA_kernel(const float* __restrict__ adj_vals,
                                                    const int* __restrict__ row,
                                                    const int* __restrict__ col,
                                                    uint64_t* __restrict__ coarse,
                                                    uint32_t* __restrict__ lens,
                                                    uint32_t* __restrict__ ovf_count,
                                                    uint64_t* __restrict__ ovf) {
  __shared__ uint32_t cnt[NB];
  int wg = blockIdx.x;
  int tid = threadIdx.x;
  if (tid < NB) cnt[tid] = 0;
  __syncthreads();
  int e0 = wg * EPW;
  int e1 = e0 + EPW;
  for (int e = e0 + tid; e < e1; e += 256) {
    if (!edge_keep((uint32_t)e)) continue;
    float v = adj_vals[e] / 0.9f;
    uint32_t r = (uint32_t)row[e];
    uint32_t c = (uint32_t)col[e];
    uint32_t b = r >> RSHIFT;
    uint32_t li = atomicAdd(&cnt[b], 1u);
    uint64_t p = ((uint64_t)r << 48) | ((uint64_t)c << 32) | (uint64_t)__float_as_uint(v);
    if (li < CAPW) {
      coarse[((size_t)b * NWG_A + wg) * CAPW + li] = p;
    } else {
      uint32_t oi = atomicAdd(ovf_count, 1u);
      if (oi < OVF_CAP) ovf[oi] = p;
    }
  }
  __syncthreads();
  if (tid < NB) lens[(size_t)tid * NWG_A + wg] = min(cnt[tid], (uint32_t)CAPW);
}

// Pass B: one 1024-thread workgroup per coarse bucket (16 waves for latency hiding).
// Scan segment lengths, flattened sweep, scatter into per-row slots (256 KB window,
// L2-merged). Rows zero-padded to a multiple of 8 slots for the branchless gather.
__global__ void __launch_bounds__(1024) partB_kernel(const uint64_t* __restrict__ coarse,
                                                     const uint32_t* __restrict__ lens,
                                                     uint64_t* __restrict__ payload,
                                                     uint32_t* __restrict__ cursor,
                                                     uint32_t* __restrict__ ovf_count,
                                                     uint64_t* __restrict__ ovf) {
  int b = blockIdx.x;
  int tid = threadIdx.x;
  __shared__ uint32_t s[NWG_A];    // inclusive scan of segment lengths
  __shared__ uint32_t cnt[512];    // per local-row fill count
  if (tid < NWG_A) s[tid] = lens[(size_t)b * NWG_A + tid];
  if (tid < 512) cnt[tid] = 0;
  __syncthreads();
  for (int off = 1; off < NWG_A; off <<= 1) {
    uint32_t v = 0, u = 0;
    if (tid < NWG_A) {
      v = s[tid];
      u = (tid >= off) ? s[tid - off] : 0u;
    }
    __syncthreads();
    if (tid < NWG_A) s[tid] = v + u;
    __syncthreads();
  }
  uint32_t total = s[NWG_A - 1];
  for (uint32_t t = tid; t < total; t += 1024) {
    int lo = 0, hi = NWG_A - 1;
    while (lo < hi) {  // smallest seg with inclusive_prefix > t
      int mid = (lo + hi) >> 1;
      if (s[mid] > t) hi = mid; else lo = mid + 1;
    }
    uint32_t prev = lo ? s[lo - 1] : 0u;
    uint64_t p = coarse[((size_t)b * NWG_A + lo) * CAPW + (t - prev)];
    uint32_t r = (uint32_t)(p >> 48);
    uint32_t rl = r - ((uint32_t)b << RSHIFT);
    uint32_t idx = atomicAdd(&cnt[rl], 1u);
    if (idx < CAP) {
      payload[(size_t)r * CAP + idx] = p & 0x0000FFFFFFFFFFFFull;  // (col<<32)|val
    } else {
      uint32_t oi = atomicAdd(ovf_count, 1u);
      if (oi < OVF_CAP) ovf[oi] = p;
    }
  }
  __syncthreads();
  // finalize cursors; zero-pad each row's slots to a multiple of 8
  for (int k = tid; k < 512; k += 1024) {
    uint32_t r = ((uint32_t)b << RSHIFT) + (uint32_t)k;
    if (r < N_NODES) {
      uint32_t c0 = min(cnt[k], (uint32_t)CAP);
      cursor[r] = r * CAP + c0;
      uint32_t np = min((c0 + 7u) & ~7u, (uint32_t)CAP);
      for (uint32_t i2 = c0; i2 < np; ++i2) payload[(size_t)r * CAP + i2] = 0ull;
    }
  }
}

// Gather, shuffle-broadcast form: lane l holds payload entry base+l; 8-wide
// blocks of shuffles produce 8 INDEPENDENT x-row loads in flight per wave.
// Rows are zero-padded to a multiple of 8 slots by partB, so no tails.
__global__ void __launch_bounds__(128) gather_shfl_kernel(const float* __restrict__ x,
                                                          const uint64_t* __restrict__ payload,
                                                          const uint32_t* __restrict__ cursor,
                                                          float* __restrict__ out) {
  int r = blockIdx.x * 4 + (threadIdx.x >> 5);
  int lane = threadIdx.x & 31;
  uint32_t base = (uint32_t)r * CAP;
  uint32_t cnt = cursor[r] - base;            // true count, <= CAP
  uint32_t n = (cnt + 7u) & ~7u;              // padded count; pads are zeros
  const float4* x4 = (const float4*)x;
  float4 acc = make_float4(0.f, 0.f, 0.f, 0.f);

  uint64_t p = payload[base + lane];          // coalesced; one load covers 32 slots
  int pc = (int)(p >> 32);
  float pv = __uint_as_float((uint32_t)p);

  int n0 = (int)min(n, 32u);
  for (int j = 0; j < n0; j += 8) {
    int   c0 = __shfl(pc, j + 0, 32); float v0 = __shfl(pv, j + 0, 32);
    int   c1 = __shfl(pc, j + 1, 32); float v1 = __shfl(pv, j + 1, 32);
    int   c2 = __shfl(pc, j + 2, 32); float v2 = __shfl(pv, j + 2, 32);
    int   c3 = __shfl(pc, j + 3, 32); float v3 = __shfl(pv, j + 3, 32);
    int   c4 = __shfl(pc, j + 4, 32); float v4 = __shfl(pv, j + 4, 32);
    int   c5 = __shfl(pc, j + 5, 32); float v5 = __shfl(pv, j + 5, 32);
    int   c6 = __shfl(pc, j + 6, 32); float v6 = __shfl(pv, j + 6, 32);
    int   c7 = __shfl(pc, j + 7, 32); float v7 = __shfl(pv, j + 7, 32);
    float4 a0 = x4[(size_t)c0 * 32 + lane];
    float4 a1 = x4[(size_t)c1 * 32 + lane];
    float4 a2 = x4[(size_t)c2 * 32 + lane];
    float4 a3 = x4[(size_t)c3 * 32 + lane];
    float4 a4 = x4[(size_t)c4 * 32 + lane];
    float4 a5 = x4[(size_t)c5 * 32 + lane];
    float4 a6 = x4[(size_t)c6 * 32 + lane];
    float4 a7 = x4[(size_t)c7 * 32 + lane];
    acc.x += v0 * a0.x; acc.y += v0 * a0.y; acc.z += v0 * a0.z; acc.w += v0 * a0.w;
    acc.x += v1 * a1.x; acc.y += v1 * a1.y; acc.z += v1 * a1.z; acc.w += v1 * a1.w;
    acc.x += v2 * a2.x; acc.y += v2 * a2.y; acc.z += v2 * a2.z; acc.w += v2 * a2.w;
    acc.x += v3 * a3.x; acc.y += v3 * a3.y; acc.z += v3 * a3.z; acc.w += v3 * a3.w;
    acc.x += v4 * a4.x; acc.y += v4 * a4.y; acc.z += v4 * a4.z; acc.w += v4 * a4.w;
    acc.x += v5 * a5.x; acc.y += v5 * a5.y; acc.z += v5 * a5.z; acc.w += v5 * a5.w;
    acc.x += v6 * a6.x; acc.y += v6 * a6.y; acc.z += v6 * a6.z; acc.w += v6 * a6.w;
    acc.x += v7 * a7.x; acc.y += v7 * a7.y; acc.z += v7 * a7.z; acc.w += v7 * a7.w;
  }
  if (n > 32) {
    uint64_t q = payload[base + 32 + lane];
    int qc = (int)(q >> 32);
    float qv = __uint_as_float((uint32_t)q);
    int n1 = (int)(n - 32u);
    for (int j = 0; j < n1; j += 8) {
      int   c0 = __shfl(qc, j + 0, 32); float v0 = __shfl(qv, j + 0, 32);
      int   c1 = __shfl(qc, j + 1, 32); float v1 = __shfl(qv, j + 1, 32);
      int   c2 = __shfl(qc, j + 2, 32); float v2 = __shfl(qv, j + 2, 32);
      int   c3 = __shfl(qc, j + 3, 32); float v3 = __shfl(qv, j + 3, 32);
      int   c4 = __shfl(qc, j + 4, 32); float v4 = __shfl(qv, j + 4, 32);
      int   c5 = __shfl(qc, j + 5, 32); float v5 = __shfl(qv, j + 5, 32);
      int   c6 = __shfl(qc, j + 6, 32); float v6 = __shfl(qv, j + 6, 32);
      int   c7 = __shfl(qc, j + 7, 32); float v7 = __shfl(qv, j + 7, 32);
      float4 a0 = x4[(size_t)c0 * 32 + lane];
      float4 a1 = x4[(size_t)c1 * 32 + lane];
      float4 a2 = x4[(size_t)c2 * 32 + lane];
      float4 a3 = x4[(size_t)c3 * 32 + lane];
      float4 a4 = x4[(size_t)c4 * 32 + lane];
      float4 a5 = x4[(size_t)c5 * 32 + lane];
      float4 a6 = x4[(size_t)c6 * 32 + lane];
      float4 a7 = x4[(size_t)c7 * 32 + lane];
      acc.x += v0 * a0.x; acc.y += v0 * a0.y; acc.z += v0 * a0.z; acc.w += v0 * a0.w;
      acc.x += v1 * a1.x; acc.y += v1 * a1.y; acc.z += v1 * a1.z; acc.w += v1 * a1.w;
      acc.x += v2 * a2.x; acc.y += v2 * a2.y; acc.z += v2 * a2.z; acc.w += v2 * a2.w;
      acc.x += v3 * a3.x; acc.y += v3 * a3.y; acc.z += v3 * a3.z; acc.w += v3 * a3.w;
      acc.x += v4 * a4.x; acc.y += v4 * a4.y; acc.z += v4 * a4.z; acc.w += v4 * a4.w;
      acc.x += v5 * a5.x; acc.y += v5 * a5.y; acc.z += v5 * a5.z; acc.w += v5 * a5.w;
      acc.x += v6 * a6.x; acc.y += v6 * a6.y; acc.z += v6 * a6.z; acc.w += v6 * a6.w;
      acc.x += v7 * a7.x; acc.y += v7 * a7.y; acc.z += v7 * a7.z; acc.w += v7 * a7.w;
    }
  }
  ((float4*)out)[(size_t)r * 32 + lane] = acc;  // writes every row: no d_out memset
}

// exact cleanup for packed (row,col,val) overflow entries (expected: none)
__global__ void __launch_bounds__(256) ovf_pack_kernel(const float* __restrict__ x,
                                                       const uint32_t* __restrict__ ovf_count,
                                                       const uint64_t* __restrict__ ovf,
                                                       float* __restrict__ out) {
  uint32_t n = *ovf_count;
  if (n > OVF_CAP) n = OVF_CAP;
  int g = (int)((blockIdx.x * blockDim.x + threadIdx.x) >> 7);
  int f = threadIdx.x & 127;
  const int ngroups = (64 * 256) >> 7;
  for (uint32_t oi = g; oi < n; oi += ngroups) {
    uint64_t p = ovf[oi];
    uint32_t r = (uint32_t)(p >> 48);
    uint32_t c = (uint32_t)((p >> 32) & 0xFFFFu);
    float v = __uint_as_float((uint32_t)p);
    atomicAdd(&out[(size_t)r * N_FEAT + f], v * x[(size_t)c * N_FEAT + f]);
  }
}

// =================== FALLBACK 1: R4 direct-scatter buckets =====================

__global__ void __launch_bounds__(256) init_kernel(uint32_t* __restrict__ cursor,
                                                   uint32_t* __restrict__ ovf_count) {
  int i = blockIdx.x * blockDim.x + threadIdx.x;
  if (i < N_NODES) cursor[i] = (uint32_t)i * CAP;
  if (i == 0) *ovf_count = 0;
}

__global__ void __launch_bounds__(256) bin_bucket_kernel(const float* __restrict__ adj_vals,
                                                         const int* __restrict__ row,
                                                         const int* __restrict__ col,
                                                         uint32_t* __restrict__ cursor,
                                                         uint64_t* __restrict__ payload,
                                                         uint32_t* __restrict__ ovf_count,
                                                         uint32_t* __restrict__ ovf) {
  int e = blockIdx.x * blockDim.x + threadIdx.x;
  if (e >= N_EDGES) return;
  if (!edge_keep((uint32_t)e)) return;
  float v = adj_vals[e] / 0.9f;
  int r = row[e];
  uint32_t pos = atomicAdd(&cursor[r], 1u);
  if (pos < (uint32_t)r * CAP + CAP) {
    payload[pos] = ((uint64_t)(uint32_t)col[e] << 32) | (uint64_t)__float_as_uint(v);
  } else {
    uint32_t oi = atomicAdd(ovf_count, 1u);
    if (oi < OVF_CAP) ovf[oi] = (uint32_t)e;
  }
}

// classic 2-deep gather (fallback path; no padding guarantee)
__global__ void __launch_bounds__(128) gather_bucket_kernel(const float* __restrict__ x,
                                                            const uint64_t* __restrict__ payload,
                                                            const uint32_t* __restrict__ cursor,
                                                            float* __restrict__ out) {
  int r = blockIdx.x * 4 + (threadIdx.x >> 5);
  int lane = threadIdx.x & 31;
  uint32_t base = (uint32_t)r * CAP;
  uint32_t end = cursor[r];
  uint32_t cap_end = base + CAP;
  if (end > cap_end) end = cap_end;
  const float4* x4 = (const float4*)x;
  float4 acc = make_float4(0.f, 0.f, 0.f, 0.f);
  uint32_t i = base;
  for (; i + 2 <= end; i += 2) {
    uint64_t p0 = payload[i];
    uint64_t p1 = payload[i + 1];
    int c0 = (int)(p0 >> 32);
    int c1 = (int)(p1 >> 32);
    float v0 = __uint_as_float((uint32_t)p0);
    float v1 = __uint_as_float((uint32_t)p1);
    float4 a0 = x4[(size_t)c0 * 32 + lane];
    float4 a1 = x4[(size_t)c1 * 32 + lane];
    acc.x += v0 * a0.x; acc.y += v0 * a0.y; acc.z += v0 * a0.z; acc.w += v0 * a0.w;
    acc.x += v1 * a1.x; acc.y += v1 * a1.y; acc.z += v1 * a1.z; acc.w += v1 * a1.w;
  }
  if (i < end) {
    uint64_t p0 = payload[i];
    int c0 = (int)(p0 >> 32);
    float v0 = __uint_as_float((uint32_t)p0);
    float4 a0 = x4[(size_t)c0 * 32 + lane];
    acc.x += v0 * a0.x; acc.y += v0 * a0.y; acc.z += v0 * a0.z; acc.w += v0 * a0.w;
  }
  ((float4*)out)[(size_t)r * 32 + lane] = acc;
}

__global__ void __launch_bounds__(256) ovf_edge_kernel(const float* __restrict__ x,
                                                       const float* __restrict__ adj_vals,
                                                       const int* __restrict__ row,
                                                       const int* __restrict__ col,
                                                       const uint32_t* __restrict__ ovf_count,
                                                       const uint32_t* __restrict__ ovf,
                                                       float* __restrict__ out) {
  uint32_t n = *ovf_count;
  if (n > OVF_CAP) n = OVF_CAP;
  int g = (int)((blockIdx.x * blockDim.x + threadIdx.x) >> 7);
  int f = threadIdx.x & 127;
  const int ngroups = (64 * 256) >> 7;
  for (uint32_t oi = g; oi < n; oi += ngroups) {
    int e = (int)ovf[oi];
    float v = adj_vals[e] / 0.9f;
    atomicAdd(&out[(size_t)row[e] * N_FEAT + f], v * x[(size_t)col[e] * N_FEAT + f]);
  }
}

// =================== FALLBACK 2: fused atomic scatter ==========================

__global__ void __launch_bounds__(256) scatter_fused_kernel(const float* __restrict__ x,
                                                            const float* __restrict__ adj_vals,
                                                            const int* __restrict__ row,
                                                            const int* __restrict__ col,
                                                            float* __restrict__ out) {
  long long t = (long long)blockIdx.x * blockDim.x + threadIdx.x;
  int e = (int)(t >> 6);
  int lane = (int)(t & 63);
  if (e >= N_EDGES) return;
  if (!edge_keep((uint32_t)e)) return;
  float v = adj_vals[e] / 0.9f;
  float2 xf = *(const float2*)(x + (long long)col[e] * N_FEAT + lane * 2);
  float* dst = out + (long long)row[e] * N_FEAT + lane * 2;
  atomicAdd(dst, v * xf.x);
  atomicAdd(dst + 1, v * xf.y);
}

// ---------------- launch --------------------------------------------------------

extern "C" void kernel_launch(void* const* d_in, const int* in_sizes, int n_in,
                              void* d_out, int out_size, void* d_ws, size_t ws_size,
                              hipStream_t stream) {
  const float* x        = (const float*)d_in[0];
  const float* adj_vals = (const float*)d_in[1];
  const int*   row      = (const int*)d_in[2];
  const int*   col      = (const int*)d_in[3];
  float* out = (float*)d_out;

  // ---- radix-path workspace layout ----
  size_t a_cursor  = 0;                                                  // N u32
  size_t a_ovfc    = (a_cursor + (size_t)N_NODES * 4 + 255) & ~255ull;   // 1 u32
  size_t a_ovf     = (a_ovfc + 4 + 255) & ~255ull;                       // OVF_CAP u64
  size_t a_lens    = (a_ovf + (size_t)OVF_CAP * 8 + 255) & ~255ull;      // NB*NWG_A u32
  size_t a_coarse  = (a_lens + (size_t)NB * NWG_A * 4 + 255) & ~255ull;  // NB*NWG_A*CAPW u64
  size_t a_payload = (a_coarse + (size_t)NB * NWG_A * CAPW * 8 + 255) & ~255ull;  // N*CAP u64
  size_t radix_need = a_payload + (size_t)N_NODES * CAP * 8;

  // ---- R4 bucket-path workspace layout ----
  size_t b_cursor  = 0;
  size_t b_ovfc    = (b_cursor + (size_t)N_NODES * 4 + 255) & ~255ull;
  size_t b_ovf     = (b_ovfc + 4 + 255) & ~255ull;
  size_t b_payload = (b_ovf + (size_t)OVF_CAP * 4 + 255) & ~255ull;
  size_t bucket_need = b_payload + (size_t)N_NODES * CAP * 8;

  if (ws_size >= radix_need) {
    uint32_t* cursor    = (uint32_t*)((char*)d_ws + a_cursor);
    uint32_t* ovf_count = (uint32_t*)((char*)d_ws + a_ovfc);
    uint64_t* ovf       = (uint64_t*)((char*)d_ws + a_ovf);
    uint32_t* lens      = (uint32_t*)((char*)d_ws + a_lens);
    uint64_t* coarse    = (uint64_t*)((char*)d_ws + a_coarse);
    uint64_t* payload   = (uint64_t*)((char*)d_ws + a_payload);

    hipMemsetAsync(ovf_count, 0, 4, stream);
    partA_kernel<<<NWG_A, 256, 0, stream>>>(adj_vals, row, col, coarse, lens, ovf_count, ovf);
    partB_kernel<<<NB, 1024, 0, stream>>>(coarse, lens, payload, cursor, ovf_count, ovf);
    gather_shfl_kernel<<<N_NODES / 4, 128, 0, stream>>>(x, payload, cursor, out);
    ovf_pack_kernel<<<64, 256, 0, stream>>>(x, ovf_count, ovf, out);
  } else if (ws_size >= bucket_need) {
    uint32_t* cursor    = (uint32_t*)((char*)d_ws + b_cursor);
    uint32_t* ovf_count = (uint32_t*)((char*)d_ws + b_ovfc);
    uint32_t* ovf       = (uint32_t*)((char*)d_ws + b_ovf);
    uint64_t* payload   = (uint64_t*)((char*)d_ws + b_payload);

    init_kernel<<<(N_NODES + 255) / 256, 256, 0, stream>>>(cursor, ovf_count);
    bin_bucket_kernel<<<(N_EDGES + 255) / 256, 256, 0, stream>>>(
        adj_vals, row, col, cursor, payload, ovf_count, ovf);
    gather_bucket_kernel<<<N_NODES / 4, 128, 0, stream>>>(x, payload, cursor, out);
    ovf_edge_kernel<<<64, 256, 0, stream>>>(x, adj_vals, row, col, ovf_count, ovf, out);
  } else {
    hipMemsetAsync(d_out, 0, (size_t)out_size * sizeof(float), stream);
    long long total_threads = (long long)N_EDGES * 64;
    scatter_fused_kernel<<<(int)((total_threads + 255) / 256), 256, 0, stream>>>(
        x, adj_vals, row, col, out);
  }
}

// Round 7
// 178.897 us; speedup vs baseline: 7.0684x; 1.2205x over previous
//
#include <hip/hip_runtime.h>
#include <stdint.h>

#define N_NODES 50000
#define N_EDGES 1600000
#define N_FEAT 128
#define CAP 64            // final bucket slots per row; Poisson(28.8) mean, +6.5 sigma
#define OVF_CAP 65536     // overflow list capacity (expected usage: ~0)

// radix-partition parameters
#define NB 98             // coarse buckets = ceil(50000 / 512)
#define RSHIFT 9          // 512 rows per coarse bucket
#define NWG_A 256         // pass-A workgroups (one segment set each)
#define CAPW 88           // slots per (bucket, wg) segment; mean 57.6, +4 sigma
#define EPW (N_EDGES / NWG_A)  // 6250 edges per pass-A workgroup

// ---------------- threefry2x32 (bit-exact, KAT-verified vs Random123) ----------

struct KeyPair { uint32_t a, b; };

__host__ __device__ constexpr inline uint32_t rotl32(uint32_t x, int r) {
  return (x << r) | (x >> (32 - r));
}

__host__ __device__ constexpr inline KeyPair threefry2x32(uint32_t k0, uint32_t k1,
                                                          uint32_t x0, uint32_t x1) {
  const uint32_t ks0 = k0, ks1 = k1, ks2 = k0 ^ k1 ^ 0x1BD11BDAu;
  x0 += ks0;
  x1 += ks1;
  const int rotA[4] = {13, 15, 26, 6};
  const int rotB[4] = {17, 29, 16, 24};
  const uint32_t ks[3] = {ks0, ks1, ks2};
  for (int i = 0; i < 5; ++i) {
    const int* rot = (i & 1) ? rotB : rotA;
    for (int j = 0; j < 4; ++j) {
      x0 += x1;
      x1 = rotl32(x1, rot[j]);
      x1 ^= x0;
    }
    x0 += ks[(i + 1) % 3];
    x1 += ks[(i + 2) % 3] + (uint32_t)(i + 1);
  }
  return {x0, x1};
}

// mask_key = fold_in(key(42), 7); compile-time.
constexpr KeyPair MASK_KEY = threefry2x32(0u, 42u, 0u, 7u);

// Partitionable (counter-mode) random_bits: element i -> threefry(key, (0, i)), bits = b1^b2.
__device__ inline bool edge_keep(uint32_t e) {
  KeyPair r = threefry2x32(MASK_KEY.a, MASK_KEY.b, 0u, e);
  uint32_t bits = r.a ^ r.b;
  float u = __uint_as_float((bits >> 9) | 0x3f800000u) - 1.0f;
  return u < 0.9f;
}

// fp32 -> bf16 with round-to-nearest-even
__device__ inline uint32_t f2bf(uint32_t b) {
  return (b + 0x7fffu + ((b >> 16) & 1u)) >> 16;
}

// =================== PRIMARY PATH: radix partition + bf16 gather ===============
// pack: (row << 48) | (col << 32) | f32bits(val)   [row, col < 65536]

// x fp32 -> packed bf16 (two per u32). 1.6M threads x float4.
__global__ void __launch_bounds__(256) conv_bf16_kernel(const float* __restrict__ x,
                                                        uint32_t* __restrict__ xb) {
  int i = blockIdx.x * blockDim.x + threadIdx.x;  // one thread -> 4 floats -> uint2
  if (i >= (N_NODES * N_FEAT) / 4) return;
  float4 f = ((const float4*)x)[i];
  uint2 o;
  o.x = f2bf(__float_as_uint(f.x)) | (f2bf(__float_as_uint(f.y)) << 16);
  o.y = f2bf(__float_as_uint(f.z)) | (f2bf(__float_as_uint(f.w)) << 16);
  ((uint2*)xb)[i] = o;
}

// Pass A: per-workgroup private compaction into (bucket, wg) segments.
__global__ void __launch_bounds__(256) partA_kernel(const float* __restrict__ adj_vals,
                                                    const int* __restrict__ row,
                                                    const int* __restrict__ col,
                                                    uint64_t* __restrict__ coarse,
                                                    uint32_t* __restrict__ lens,
                                                    uint32_t* __restrict__ ovf_count,
                                                    uint64_t* __restrict__ ovf) {
  __shared__ uint32_t cnt[NB];
  int wg = blockIdx.x;
  int tid = threadIdx.x;
  if (tid < NB) cnt[tid] = 0;
  __syncthreads();
  int e0 = wg * EPW;
  int e1 = e0 + EPW;
  for (int e = e0 + tid; e < e1; e += 256) {
    if (!edge_keep((uint32_t)e)) continue;
    float v = adj_vals[e] / 0.9f;
    uint32_t r = (uint32_t)row[e];
    uint32_t c = (uint32_t)col[e];
    uint32_t b = r >> RSHIFT;
    uint32_t li = atomicAdd(&cnt[b], 1u);
    uint64_t p = ((uint64_t)r << 48) | ((uint64_t)c << 32) | (uint64_t)__float_as_uint(v);
    if (li < CAPW) {
      coarse[((size_t)b * NWG_A + wg) * CAPW + li] = p;
    } else {
      uint32_t oi = atomicAdd(ovf_count, 1u);
      if (oi < OVF_CAP) ovf[oi] = p;
    }
  }
  __syncthreads();
  if (tid < NB) lens[(size_t)tid * NWG_A + wg] = min(cnt[tid], (uint32_t)CAPW);
}

// Pass B: one 1024-thread workgroup per coarse bucket; scatter into per-row slots.
// Rows zero-padded to a multiple of 8 slots for the branchless gather.
__global__ void __launch_bounds__(1024) partB_kernel(const uint64_t* __restrict__ coarse,
                                                     const uint32_t* __restrict__ lens,
                                                     uint64_t* __restrict__ payload,
                                                     uint32_t* __restrict__ cursor,
                                                     uint32_t* __restrict__ ovf_count,
                                                     uint64_t* __restrict__ ovf) {
  int b = blockIdx.x;
  int tid = threadIdx.x;
  __shared__ uint32_t s[NWG_A];    // inclusive scan of segment lengths
  __shared__ uint32_t cnt[512];    // per local-row fill count
  if (tid < NWG_A) s[tid] = lens[(size_t)b * NWG_A + tid];
  if (tid < 512) cnt[tid] = 0;
  __syncthreads();
  for (int off = 1; off < NWG_A; off <<= 1) {
    uint32_t v = 0, u = 0;
    if (tid < NWG_A) {
      v = s[tid];
      u = (tid >= off) ? s[tid - off] : 0u;
    }
    __syncthreads();
    if (tid < NWG_A) s[tid] = v + u;
    __syncthreads();
  }
  uint32_t total = s[NWG_A - 1];
  for (uint32_t t = tid; t < total; t += 1024) {
    int lo = 0, hi = NWG_A - 1;
    while (lo < hi) {  // smallest seg with inclusive_prefix > t
      int mid = (lo + hi) >> 1;
      if (s[mid] > t) hi = mid; else lo = mid + 1;
    }
    uint32_t prev = lo ? s[lo - 1] : 0u;
    uint64_t p = coarse[((size_t)b * NWG_A + lo) * CAPW + (t - prev)];
    uint32_t r = (uint32_t)(p >> 48);
    uint32_t rl = r - ((uint32_t)b << RSHIFT);
    uint32_t idx = atomicAdd(&cnt[rl], 1u);
    if (idx < CAP) {
      payload[(size_t)r * CAP + idx] = p & 0x0000FFFFFFFFFFFFull;  // (col<<32)|val
    } else {
      uint32_t oi = atomicAdd(ovf_count, 1u);
      if (oi < OVF_CAP) ovf[oi] = p;
    }
  }
  __syncthreads();
  // finalize cursors; zero-pad each row's slots to a multiple of 8
  for (int k = tid; k < 512; k += 1024) {
    uint32_t r = ((uint32_t)b << RSHIFT) + (uint32_t)k;
    if (r < N_NODES) {
      uint32_t c0 = min(cnt[k], (uint32_t)CAP);
      cursor[r] = r * CAP + c0;
      uint32_t np = min((c0 + 7u) & ~7u, (uint32_t)CAP);
      for (uint32_t i2 = c0; i2 < np; ++i2) payload[(size_t)r * CAP + i2] = 0ull;
    }
  }
}

// Gather from bf16 x: 32-lane teams per row, 8 teams per 256-thread block.
// lane l holds payload slot base+l; 8-wide shuffle blocks -> 8 independent
// x-row loads (uint2 = 4 bf16 feats/lane) in flight; fp32 accumulate.
__global__ void __launch_bounds__(256) gather_bf16_kernel(const uint32_t* __restrict__ xb,
                                                          const uint64_t* __restrict__ payload,
                                                          const uint32_t* __restrict__ cursor,
                                                          float* __restrict__ out) {
  int r = blockIdx.x * 8 + (threadIdx.x >> 5);
  int lane = threadIdx.x & 31;
  uint32_t base = (uint32_t)r * CAP;
  uint32_t cnt = cursor[r] - base;            // true count, <= CAP
  uint32_t n = (cnt + 7u) & ~7u;              // padded count; pads are zeros
  const uint2* x2 = (const uint2*)xb;         // row stride: 32 uint2 (128 bf16)
  float4 acc = make_float4(0.f, 0.f, 0.f, 0.f);

  uint64_t p = payload[base + lane];          // coalesced; one load covers 32 slots
  int pc = (int)(p >> 32);
  float pv = __uint_as_float((uint32_t)p);

#define GSTEP(cc, vv)                                                        \
  {                                                                          \
    uint2 a = x2[(size_t)(cc) * 32 + lane];                                  \
    float f0 = __uint_as_float(a.x << 16);                                   \
    float f1 = __uint_as_float(a.x & 0xffff0000u);                           \
    float f2 = __uint_as_float(a.y << 16);                                   \
    float f3 = __uint_as_float(a.y & 0xffff0000u);                           \
    acc.x += (vv) * f0; acc.y += (vv) * f1;                                  \
    acc.z += (vv) * f2; acc.w += (vv) * f3;                                  \
  }

  int n0 = (int)min(n, 32u);
  for (int j = 0; j < n0; j += 8) {
    int   c0 = __shfl(pc, j + 0, 32); float v0 = __shfl(pv, j + 0, 32);
    int   c1 = __shfl(pc, j + 1, 32); float v1 = __shfl(pv, j + 1, 32);
    int   c2 = __shfl(pc, j + 2, 32); float v2 = __shfl(pv, j + 2, 32);
    int   c3 = __shfl(pc, j + 3, 32); float v3 = __shfl(pv, j + 3, 32);
    int   c4 = __shfl(pc, j + 4, 32); float v4 = __shfl(pv, j + 4, 32);
    int   c5 = __shfl(pc, j + 5, 32); float v5 = __shfl(pv, j + 5, 32);
    int   c6 = __shfl(pc, j + 6, 32); float v6 = __shfl(pv, j + 6, 32);
    int   c7 = __shfl(pc, j + 7, 32); float v7 = __shfl(pv, j + 7, 32);
    GSTEP(c0, v0) GSTEP(c1, v1) GSTEP(c2, v2) GSTEP(c3, v3)
    GSTEP(c4, v4) GSTEP(c5, v5) GSTEP(c6, v6) GSTEP(c7, v7)
  }
  if (n > 32) {
    uint64_t q = payload[base + 32 + lane];
    int qc = (int)(q >> 32);
    float qv = __uint_as_float((uint32_t)q);
    int n1 = (int)(n - 32u);
    for (int j = 0; j < n1; j += 8) {
      int   c0 = __shfl(qc, j + 0, 32); float v0 = __shfl(qv, j + 0, 32);
      int   c1 = __shfl(qc, j + 1, 32); float v1 = __shfl(qv, j + 1, 32);
      int   c2 = __shfl(qc, j + 2, 32); float v2 = __shfl(qv, j + 2, 32);
      int   c3 = __shfl(qc, j + 3, 32); float v3 = __shfl(qv, j + 3, 32);
      int   c4 = __shfl(qc, j + 4, 32); float v4 = __shfl(qv, j + 4, 32);
      int   c5 = __shfl(qc, j + 5, 32); float v5 = __shfl(qv, j + 5, 32);
      int   c6 = __shfl(qc, j + 6, 32); float v6 = __shfl(qv, j + 6, 32);
      int   c7 = __shfl(qc, j + 7, 32); float v7 = __shfl(qv, j + 7, 32);
      GSTEP(c0, v0) GSTEP(c1, v1) GSTEP(c2, v2) GSTEP(c3, v3)
      GSTEP(c4, v4) GSTEP(c5, v5) GSTEP(c6, v6) GSTEP(c7, v7)
    }
  }
#undef GSTEP
  ((float4*)out)[(size_t)r * 32 + lane] = acc;  // writes every row: no d_out memset
}

// exact cleanup for packed (row,col,val) overflow entries (expected: none)
__global__ void __launch_bounds__(256) ovf_pack_kernel(const float* __restrict__ x,
                                                       const uint32_t* __restrict__ ovf_count,
                                                       const uint64_t* __restrict__ ovf,
                                                       float* __restrict__ out) {
  uint32_t n = *ovf_count;
  if (n > OVF_CAP) n = OVF_CAP;
  int g = (int)((blockIdx.x * blockDim.x + threadIdx.x) >> 7);
  int f = threadIdx.x & 127;
  const int ngroups = (64 * 256) >> 7;
  for (uint32_t oi = g; oi < n; oi += ngroups) {
    uint64_t p = ovf[oi];
    uint32_t r = (uint32_t)(p >> 48);
    uint32_t c = (uint32_t)((p >> 32) & 0xFFFFu);
    float v = __uint_as_float((uint32_t)p);
    atomicAdd(&out[(size_t)r * N_FEAT + f], v * x[(size_t)c * N_FEAT + f]);
  }
}

// =================== FALLBACK 1: radix + fp32 gather (R6 code) =================

__global__ void __launch_bounds__(128) gather_shfl_kernel(const float* __restrict__ x,
                                                          const uint64_t* __restrict__ payload,
                                                          const uint32_t* __restrict__ cursor,
                                                          float* __restrict__ out) {
  int r = blockIdx.x * 4 + (threadIdx.x >> 5);
  int lane = threadIdx.x & 31;
  uint32_t base = (uint32_t)r * CAP;
  uint32_t cnt = cursor[r] - base;
  uint32_t n = (cnt + 7u) & ~7u;
  const float4* x4 = (const float4*)x;
  float4 acc = make_float4(0.f, 0.f, 0.f, 0.f);
  uint64_t p = payload[base + lane];
  int pc = (int)(p >> 32);
  float pv = __uint_as_float((uint32_t)p);
  int n0 = (int)min(n, 32u);
  for (int j = 0; j < n0; j += 8) {
    int   c0 = __shfl(pc, j + 0, 32); float v0 = __shfl(pv, j + 0, 32);
    int   c1 = __shfl(pc, j + 1, 32); float v1 = __shfl(pv, j + 1, 32);
    int   c2 = __shfl(pc, j + 2, 32); float v2 = __shfl(pv, j + 2, 32);
    int   c3 = __shfl(pc, j + 3, 32); float v3 = __shfl(pv, j + 3, 32);
    int   c4 = __shfl(pc, j + 4, 32); float v4 = __shfl(pv, j + 4, 32);
    int   c5 = __shfl(pc, j + 5, 32); float v5 = __shfl(pv, j + 5, 32);
    int   c6 = __shfl(pc, j + 6, 32); float v6 = __shfl(pv, j + 6, 32);
    int   c7 = __shfl(pc, j + 7, 32); float v7 = __shfl(pv, j + 7, 32);
    float4 a0 = x4[(size_t)c0 * 32 + lane];
    float4 a1 = x4[(size_t)c1 * 32 + lane];
    float4 a2 = x4[(size_t)c2 * 32 + lane];
    float4 a3 = x4[(size_t)c3 * 32 + lane];
    float4 a4 = x4[(size_t)c4 * 32 + lane];
    float4 a5 = x4[(size_t)c5 * 32 + lane];
    float4 a6 = x4[(size_t)c6 * 32 + lane];
    float4 a7 = x4[(size_t)c7 * 32 + lane];
    acc.x += v0 * a0.x; acc.y += v0 * a0.y; acc.z += v0 * a0.z; acc.w += v0 * a0.w;
    acc.x += v1 * a1.x; acc.y += v1 * a1.y; acc.z += v1 * a1.z; acc.w += v1 * a1.w;
    acc.x += v2 * a2.x; acc.y += v2 * a2.y; acc.z += v2 * a2.z; acc.w += v2 * a2.w;
    acc.x += v3 * a3.x; acc.y += v3 * a3.y; acc.z += v3 * a3.z; acc.w += v3 * a3.w;
    acc.x += v4 * a4.x; acc.y += v4 * a4.y; acc.z += v4 * a4.z; acc.w += v4 * a4.w;
    acc.x += v5 * a5.x; acc.y += v5 * a5.y; acc.z += v5 * a5.z; acc.w += v5 * a5.w;
    acc.x += v6 * a6.x; acc.y += v6 * a6.y; acc.z += v6 * a6.z; acc.w += v6 * a6.w;
    acc.x += v7 * a7.x; acc.y += v7 * a7.y; acc.z += v7 * a7.z; acc.w += v7 * a7.w;
  }
  if (n > 32) {
    uint64_t q = payload[base + 32 + lane];
    int qc = (int)(q >> 32);
    float qv = __uint_as_float((uint32_t)q);
    int n1 = (int)(n - 32u);
    for (int j = 0; j < n1; j += 8) {
      int   c0 = __shfl(qc, j + 0, 32); float v0 = __shfl(qv, j + 0, 32);
      int   c1 = __shfl(qc, j + 1, 32); float v1 = __shfl(qv, j + 1, 32);
      int   c2 = __shfl(qc, j + 2, 32); float v2 = __shfl(qv, j + 2, 32);
      int   c3 = __shfl(qc, j + 3, 32); float v3 = __shfl(qv, j + 3, 32);
      int   c4 = __shfl(qc, j + 4, 32); float v4 = __shfl(qv, j + 4, 32);
      int   c5 = __shfl(qc, j + 5, 32); float v5 = __shfl(qv, j + 5, 32);
      int   c6 = __shfl(qc, j + 6, 32); float v6 = __shfl(qv, j + 6, 32);
      int   c7 = __shfl(qc, j + 7, 32); float v7 = __shfl(qv, j + 7, 32);
      float4 a0 = x4[(size_t)c0 * 32 + lane];
      float4 a1 = x4[(size_t)c1 * 32 + lane];
      float4 a2 = x4[(size_t)c2 * 32 + lane];
      float4 a3 = x4[(size_t)c3 * 32 + lane];
      float4 a4 = x4[(size_t)c4 * 32 + lane];
      float4 a5 = x4[(size_t)c5 * 32 + lane];
      float4 a6 = x4[(size_t)c6 * 32 + lane];
      float4 a7 = x4[(size_t)c7 * 32 + lane];
      acc.x += v0 * a0.x; acc.y += v0 * a0.y; acc.z += v0 * a0.z; acc.w += v0 * a0.w;
      acc.x += v1 * a1.x; acc.y += v1 * a1.y; acc.z += v1 * a1.z; acc.w += v1 * a1.w;
      acc.x += v2 * a2.x; acc.y += v2 * a2.y; acc.z += v2 * a2.z; acc.w += v2 * a2.w;
      acc.x += v3 * a3.x; acc.y += v3 * a3.y; acc.z += v3 * a3.z; acc.w += v3 * a3.w;
      acc.x += v4 * a4.x; acc.y += v4 * a4.y; acc.z += v4 * a4.z; acc.w += v4 * a4.w;
      acc.x += v5 * a5.x; acc.y += v5 * a5.y; acc.z += v5 * a5.z; acc.w += v5 * a5.w;
      acc.x += v6 * a6.x; acc.y += v6 * a6.y; acc.z += v6 * a6.z; acc.w += v6 * a6.w;
      acc.x += v7 * a7.x; acc.y += v7 * a7.y; acc.z += v7 * a7.z; acc.w += v7 * a7.w;
    }
  }
  ((float4*)out)[(size_t)r * 32 + lane] = acc;
}

// =================== FALLBACK 2: fused atomic scatter ==========================

__global__ void __launch_bounds__(256) scatter_fused_kernel(const float* __restrict__ x,
                                                            const float* __restrict__ adj_vals,
                                                            const int* __restrict__ row,
                                                            const int* __restrict__ col,
                                                            float* __restrict__ out) {
  long long t = (long long)blockIdx.x * blockDim.x + threadIdx.x;
  int e = (int)(t >> 6);
  int lane = (int)(t & 63);
  if (e >= N_EDGES) return;
  if (!edge_keep((uint32_t)e)) return;
  float v = adj_vals[e] / 0.9f;
  float2 xf = *(const float2*)(x + (long long)col[e] * N_FEAT + lane * 2);
  float* dst = out + (long long)row[e] * N_FEAT + lane * 2;
  atomicAdd(dst, v * xf.x);
  atomicAdd(dst + 1, v * xf.y);
}

// ---------------- launch --------------------------------------------------------

extern "C" void kernel_launch(void* const* d_in, const int* in_sizes, int n_in,
                              void* d_out, int out_size, void* d_ws, size_t ws_size,
                              hipStream_t stream) {
  const float* x        = (const float*)d_in[0];
  const float* adj_vals = (const float*)d_in[1];
  const int*   row      = (const int*)d_in[2];
  const int*   col      = (const int*)d_in[3];
  float* out = (float*)d_out;

  // ---- radix-path workspace layout ----
  size_t a_cursor  = 0;                                                  // N u32
  size_t a_ovfc    = (a_cursor + (size_t)N_NODES * 4 + 255) & ~255ull;   // 1 u32
  size_t a_ovf     = (a_ovfc + 4 + 255) & ~255ull;                       // OVF_CAP u64
  size_t a_lens    = (a_ovf + (size_t)OVF_CAP * 8 + 255) & ~255ull;      // NB*NWG_A u32
  size_t a_coarse  = (a_lens + (size_t)NB * NWG_A * 4 + 255) & ~255ull;  // NB*NWG_A*CAPW u64
  size_t a_payload = (a_coarse + (size_t)NB * NWG_A * CAPW * 8 + 255) & ~255ull;  // N*CAP u64
  size_t radix_need = a_payload + (size_t)N_NODES * CAP * 8;
  size_t a_xb      = (radix_need + 255) & ~255ull;                       // N*F bf16
  size_t radix_bf16_need = a_xb + (size_t)N_NODES * N_FEAT * 2;

  if (ws_size >= radix_need) {
    uint32_t* cursor    = (uint32_t*)((char*)d_ws + a_cursor);
    uint32_t* ovf_count = (uint32_t*)((char*)d_ws + a_ovfc);
    uint64_t* ovf       = (uint64_t*)((char*)d_ws + a_ovf);
    uint32_t* lens      = (uint32_t*)((char*)d_ws + a_lens);
    uint64_t* coarse    = (uint64_t*)((char*)d_ws + a_coarse);
    uint64_t* payload   = (uint64_t*)((char*)d_ws + a_payload);

    hipMemsetAsync(ovf_count, 0, 4, stream);
    bool use_bf16 = (ws_size >= radix_bf16_need);
    if (use_bf16) {
      uint32_t* xb = (uint32_t*)((char*)d_ws + a_xb);
      conv_bf16_kernel<<<(N_NODES * N_FEAT / 4 + 255) / 256, 256, 0, stream>>>(x, xb);
      partA_kernel<<<NWG_A, 256, 0, stream>>>(adj_vals, row, col, coarse, lens, ovf_count, ovf);
      partB_kernel<<<NB, 1024, 0, stream>>>(coarse, lens, payload, cursor, ovf_count, ovf);
      gather_bf16_kernel<<<N_NODES / 8, 256, 0, stream>>>(xb, payload, cursor, out);
    } else {
      partA_kernel<<<NWG_A, 256, 0, stream>>>(adj_vals, row, col, coarse, lens, ovf_count, ovf);
      partB_kernel<<<NB, 1024, 0, stream>>>(coarse, lens, payload, cursor, ovf_count, ovf);
      gather_shfl_kernel<<<N_NODES / 4, 128, 0, stream>>>(x, payload, cursor, out);
    }
    ovf_pack_kernel<<<64, 256, 0, stream>>>(x, ovf_count, ovf, out);
  } else {
    hipMemsetAsync(d_out, 0, (size_t)out_size * sizeof(float), stream);
    long long total_threads = (long long)N_EDGES * 64;
    scatter_fused_kernel<<<(int)((total_threads + 255) / 256), 256, 0, stream>>>(
        x, adj_vals, row, col, out);
  }
}

// Round 8
// 169.085 us; speedup vs baseline: 7.4786x; 1.0580x over previous
//
#include <hip/hip_runtime.h>
#include <stdint.h>

#define N_NODES 50000
#define N_EDGES 1600000
#define N_FEAT 128
#define CAP 64            // final bucket slots per row; Poisson(28.8) mean, +6.5 sigma
#define OVF_CAP 65536     // overflow list capacity (expected usage: ~0)

// radix-partition parameters
#define RSHIFT 8          // 256 rows per coarse bucket
#define BROWS 256
#define NB 196            // ceil(50000 / 256)
#define NWG_A 256         // pass-A workgroups (one segment set each)
#define A_THREADS 1024    // 4 waves/SIMD in partA for latency hiding
#define CAPW 56           // slots per (bucket, wg) segment; mean 28.8, +5 sigma
#define EPW (N_EDGES / NWG_A)  // 6250 edges per pass-A workgroup

// ---------------- threefry2x32 (bit-exact, KAT-verified vs Random123) ----------

struct KeyPair { uint32_t a, b; };

__host__ __device__ constexpr inline uint32_t rotl32(uint32_t x, int r) {
  return (x << r) | (x >> (32 - r));
}

__host__ __device__ constexpr inline KeyPair threefry2x32(uint32_t k0, uint32_t k1,
                                                          uint32_t x0, uint32_t x1) {
  const uint32_t ks0 = k0, ks1 = k1, ks2 = k0 ^ k1 ^ 0x1BD11BDAu;
  x0 += ks0;
  x1 += ks1;
  const int rotA[4] = {13, 15, 26, 6};
  const int rotB[4] = {17, 29, 16, 24};
  const uint32_t ks[3] = {ks0, ks1, ks2};
  for (int i = 0; i < 5; ++i) {
    const int* rot = (i & 1) ? rotB : rotA;
    for (int j = 0; j < 4; ++j) {
      x0 += x1;
      x1 = rotl32(x1, rot[j]);
      x1 ^= x0;
    }
    x0 += ks[(i + 1) % 3];
    x1 += ks[(i + 2) % 3] + (uint32_t)(i + 1);
  }
  return {x0, x1};
}

// mask_key = fold_in(key(42), 7); compile-time.
constexpr KeyPair MASK_KEY = threefry2x32(0u, 42u, 0u, 7u);

// Partitionable (counter-mode) random_bits: element i -> threefry(key, (0, i)), bits = b1^b2.
__device__ inline bool edge_keep(uint32_t e) {
  KeyPair r = threefry2x32(MASK_KEY.a, MASK_KEY.b, 0u, e);
  uint32_t bits = r.a ^ r.b;
  float u = __uint_as_float((bits >> 9) | 0x3f800000u) - 1.0f;
  return u < 0.9f;
}

// fp32 bits -> bf16 with round-to-nearest-even
__device__ inline uint32_t f2bf(uint32_t b) {
  return (b + 0x7fffu + ((b >> 16) & 1u)) >> 16;
}

// =================== PRIMARY PATH ==============================================
// coarse pack: (row << 48) | (col << 32) | f32bits(val)
// final payload (u32): (col << 16) | bf16bits(val)

// Fused: x->bf16 conversion slice + pass-A per-workgroup compaction into
// (bucket, wg) segments. 1024 threads/wg -> 4 waves/SIMD.
__global__ void __launch_bounds__(A_THREADS) convA_kernel(const float* __restrict__ x,
                                                          uint32_t* __restrict__ xb,
                                                          const float* __restrict__ adj_vals,
                                                          const int* __restrict__ row,
                                                          const int* __restrict__ col,
                                                          uint64_t* __restrict__ coarse,
                                                          uint32_t* __restrict__ lens,
                                                          uint32_t* __restrict__ ovf_count,
                                                          uint64_t* __restrict__ ovf) {
  __shared__ uint32_t cnt[NB];
  int wg = blockIdx.x;
  int tid = threadIdx.x;
  if (tid < NB) cnt[tid] = 0;

  // phase 0: bf16 conversion (grid-stride; independent of partition data)
  const int gthreads = NWG_A * A_THREADS;
  for (int i = wg * A_THREADS + tid; i < (N_NODES * N_FEAT) / 4; i += gthreads) {
    float4 f = ((const float4*)x)[i];
    uint2 o;
    o.x = f2bf(__float_as_uint(f.x)) | (f2bf(__float_as_uint(f.y)) << 16);
    o.y = f2bf(__float_as_uint(f.z)) | (f2bf(__float_as_uint(f.w)) << 16);
    ((uint2*)xb)[i] = o;
  }
  __syncthreads();  // cnt init visible

  // phase 1: partition this wg's edge slice
  int e0 = wg * EPW;
  int e1 = e0 + EPW;
  for (int e = e0 + tid; e < e1; e += A_THREADS) {
    if (!edge_keep((uint32_t)e)) continue;
    float v = adj_vals[e] / 0.9f;
    uint32_t r = (uint32_t)row[e];
    uint32_t c = (uint32_t)col[e];
    uint32_t b = r >> RSHIFT;
    uint32_t li = atomicAdd(&cnt[b], 1u);
    uint64_t p = ((uint64_t)r << 48) | ((uint64_t)c << 32) | (uint64_t)__float_as_uint(v);
    if (li < CAPW) {
      coarse[((size_t)b * NWG_A + wg) * CAPW + li] = p;
    } else {
      uint32_t oi = atomicAdd(ovf_count, 1u);
      if (oi < OVF_CAP) ovf[oi] = p;
    }
  }
  __syncthreads();
  if (tid < NB) lens[(size_t)tid * NWG_A + wg] = min(cnt[tid], (uint32_t)CAPW);
}

// Pass B: one 1024-thread wg per 256-row bucket (196 wgs). LDS scan of the 256
// segment lengths, then 4 threads per segment place entries directly (no binary
// search). Destination window = 64 KB contiguous -> L2-merged writebacks.
__global__ void __launch_bounds__(1024) partB_kernel(const uint64_t* __restrict__ coarse,
                                                     const uint32_t* __restrict__ lens,
                                                     uint32_t* __restrict__ payload,
                                                     uint32_t* __restrict__ cursor,
                                                     uint32_t* __restrict__ ovf_count,
                                                     uint64_t* __restrict__ ovf) {
  int b = blockIdx.x;
  int tid = threadIdx.x;
  __shared__ uint32_t s[NWG_A];    // inclusive scan of segment lengths
  __shared__ uint32_t cnt[BROWS];  // per local-row fill count
  if (tid < NWG_A) s[tid] = lens[(size_t)b * NWG_A + tid];
  if (tid < BROWS) cnt[tid] = 0;
  __syncthreads();
  for (int off = 1; off < NWG_A; off <<= 1) {
    uint32_t v = 0, u = 0;
    if (tid < NWG_A) {
      v = s[tid];
      u = (tid >= off) ? s[tid - off] : 0u;
    }
    __syncthreads();
    if (tid < NWG_A) s[tid] = v + u;
    __syncthreads();
  }
  // 4 threads per segment, direct placement
  int seg = tid >> 2;
  int sub = tid & 3;
  uint32_t sbase = (seg == 0) ? 0u : s[seg - 1];
  uint32_t slen = s[seg] - sbase;
  const uint64_t* cseg = coarse + ((size_t)b * NWG_A + seg) * CAPW;
  for (uint32_t li = (uint32_t)sub; li < slen; li += 4) {
    uint64_t p = cseg[li];
    uint32_t r = (uint32_t)(p >> 48);
    uint32_t rl = r & (BROWS - 1);
    uint32_t idx = atomicAdd(&cnt[rl], 1u);
    if (idx < CAP) {
      uint32_t c = (uint32_t)(p >> 32) & 0xFFFFu;
      payload[(size_t)r * CAP + idx] = (c << 16) | f2bf((uint32_t)p);
    } else {
      uint32_t oi = atomicAdd(ovf_count, 1u);
      if (oi < OVF_CAP) ovf[oi] = p;
    }
  }
  __syncthreads();
  // finalize cursors; zero-pad each row's slots to a multiple of 8
  for (int k = tid; k < BROWS; k += 1024) {
    uint32_t r = ((uint32_t)b << RSHIFT) + (uint32_t)k;
    if (r < N_NODES) {
      uint32_t c0 = min(cnt[k], (uint32_t)CAP);
      cursor[r] = r * CAP + c0;
      uint32_t np = min((c0 + 7u) & ~7u, (uint32_t)CAP);
      for (uint32_t i2 = c0; i2 < np; ++i2) payload[(size_t)r * CAP + i2] = 0u;
    }
  }
}

// Gather from bf16 x: 32-lane teams per row, 8 teams per 256-thread block.
// lane l holds payload slot base+l (u32); 8-wide shuffle blocks -> 8 independent
// x-row loads (uint2 = 4 bf16 feats/lane) in flight; fp32 accumulate.
__global__ void __launch_bounds__(256) gather_bf16_kernel(const uint32_t* __restrict__ xb,
                                                          const uint32_t* __restrict__ payload,
                                                          const uint32_t* __restrict__ cursor,
                                                          float* __restrict__ out) {
  int r = blockIdx.x * 8 + (threadIdx.x >> 5);
  int lane = threadIdx.x & 31;
  uint32_t base = (uint32_t)r * CAP;
  uint32_t cnt = cursor[r] - base;            // true count, <= CAP
  uint32_t n = (cnt + 7u) & ~7u;              // padded count; pads are zeros
  const uint2* x2 = (const uint2*)xb;         // row stride: 32 uint2 (128 bf16)
  float4 acc = make_float4(0.f, 0.f, 0.f, 0.f);

  uint32_t p = payload[base + lane];          // coalesced; one load covers 32 slots

#define GSTEP(ww)                                                            \
  {                                                                          \
    uint32_t cc = (ww) >> 16;                                                \
    float vv = __uint_as_float((ww) << 16);                                  \
    uint2 a = x2[(size_t)cc * 32 + lane];                                    \
    float f0 = __uint_as_float(a.x << 16);                                   \
    float f1 = __uint_as_float(a.x & 0xffff0000u);                           \
    float f2 = __uint_as_float(a.y << 16);                                   \
    float f3 = __uint_as_float(a.y & 0xffff0000u);                           \
    acc.x += vv * f0; acc.y += vv * f1;                                      \
    acc.z += vv * f2; acc.w += vv * f3;                                      \
  }

  int n0 = (int)min(n, 32u);
  for (int j = 0; j < n0; j += 8) {
    uint32_t w0 = __shfl(p, j + 0, 32);
    uint32_t w1 = __shfl(p, j + 1, 32);
    uint32_t w2 = __shfl(p, j + 2, 32);
    uint32_t w3 = __shfl(p, j + 3, 32);
    uint32_t w4 = __shfl(p, j + 4, 32);
    uint32_t w5 = __shfl(p, j + 5, 32);
    uint32_t w6 = __shfl(p, j + 6, 32);
    uint32_t w7 = __shfl(p, j + 7, 32);
    GSTEP(w0) GSTEP(w1) GSTEP(w2) GSTEP(w3)
    GSTEP(w4) GSTEP(w5) GSTEP(w6) GSTEP(w7)
  }
  if (n > 32) {
    uint32_t q = payload[base + 32 + lane];
    int n1 = (int)(n - 32u);
    for (int j = 0; j < n1; j += 8) {
      uint32_t w0 = __shfl(q, j + 0, 32);
      uint32_t w1 = __shfl(q, j + 1, 32);
      uint32_t w2 = __shfl(q, j + 2, 32);
      uint32_t w3 = __shfl(q, j + 3, 32);
      uint32_t w4 = __shfl(q, j + 4, 32);
      uint32_t w5 = __shfl(q, j + 5, 32);
      uint32_t w6 = __shfl(q, j + 6, 32);
      uint32_t w7 = __shfl(q, j + 7, 32);
      GSTEP(w0) GSTEP(w1) GSTEP(w2) GSTEP(w3)
      GSTEP(w4) GSTEP(w5) GSTEP(w6) GSTEP(w7)
    }
  }
#undef GSTEP
  ((float4*)out)[(size_t)r * 32 + lane] = acc;  // writes every row: no d_out memset
}

// exact cleanup for packed (row,col,f32val) overflow entries (expected: none)
__global__ void __launch_bounds__(256) ovf_pack_kernel(const float* __restrict__ x,
                                                       const uint32_t* __restrict__ ovf_count,
                                                       const uint64_t* __restrict__ ovf,
                                                       float* __restrict__ out) {
  uint32_t n = *ovf_count;
  if (n > OVF_CAP) n = OVF_CAP;
  int g = (int)((blockIdx.x * blockDim.x + threadIdx.x) >> 7);
  int f = threadIdx.x & 127;
  const int ngroups = (64 * 256) >> 7;
  for (uint32_t oi = g; oi < n; oi += ngroups) {
    uint64_t p = ovf[oi];
    uint32_t r = (uint32_t)(p >> 48);
    uint32_t c = (uint32_t)((p >> 32) & 0xFFFFu);
    float v = __uint_as_float((uint32_t)p);
    atomicAdd(&out[(size_t)r * N_FEAT + f], v * x[(size_t)c * N_FEAT + f]);
  }
}

// =================== FALLBACK: fused atomic scatter ============================

__global__ void __launch_bounds__(256) scatter_fused_kernel(const float* __restrict__ x,
                                                            const float* __restrict__ adj_vals,
                                                            const int* __restrict__ row,
                                                            const int* __restrict__ col,
                                                            float* __restrict__ out) {
  long long t = (long long)blockIdx.x * blockDim.x + threadIdx.x;
  int e = (int)(t >> 6);
  int lane = (int)(t & 63);
  if (e >= N_EDGES) return;
  if (!edge_keep((uint32_t)e)) return;
  float v = adj_vals[e] / 0.9f;
  float2 xf = *(const float2*)(x + (long long)col[e] * N_FEAT + lane * 2);
  float* dst = out + (long long)row[e] * N_FEAT + lane * 2;
  atomicAdd(dst, v * xf.x);
  atomicAdd(dst + 1, v * xf.y);
}

// ---------------- launch --------------------------------------------------------

extern "C" void kernel_launch(void* const* d_in, const int* in_sizes, int n_in,
                              void* d_out, int out_size, void* d_ws, size_t ws_size,
                              hipStream_t stream) {
  const float* x        = (const float*)d_in[0];
  const float* adj_vals = (const float*)d_in[1];
  const int*   row      = (const int*)d_in[2];
  const int*   col      = (const int*)d_in[3];
  float* out = (float*)d_out;

  // ---- workspace layout ----
  size_t a_cursor  = 0;                                                  // N u32
  size_t a_ovfc    = (a_cursor + (size_t)N_NODES * 4 + 255) & ~255ull;   // 1 u32
  size_t a_ovf     = (a_ovfc + 4 + 255) & ~255ull;                       // OVF_CAP u64
  size_t a_lens    = (a_ovf + (size_t)OVF_CAP * 8 + 255) & ~255ull;      // NB*NWG_A u32
  size_t a_coarse  = (a_lens + (size_t)NB * NWG_A * 4 + 255) & ~255ull;  // NB*NWG_A*CAPW u64
  size_t a_payload = (a_coarse + (size_t)NB * NWG_A * CAPW * 8 + 255) & ~255ull;  // N*CAP u32
  size_t a_xb      = (a_payload + (size_t)N_NODES * CAP * 4 + 255) & ~255ull;     // N*F bf16
  size_t need      = a_xb + (size_t)N_NODES * N_FEAT * 2;

  if (ws_size >= need) {
    uint32_t* cursor    = (uint32_t*)((char*)d_ws + a_cursor);
    uint32_t* ovf_count = (uint32_t*)((char*)d_ws + a_ovfc);
    uint64_t* ovf       = (uint64_t*)((char*)d_ws + a_ovf);
    uint32_t* lens      = (uint32_t*)((char*)d_ws + a_lens);
    uint64_t* coarse    = (uint64_t*)((char*)d_ws + a_coarse);
    uint32_t* payload   = (uint32_t*)((char*)d_ws + a_payload);
    uint32_t* xb        = (uint32_t*)((char*)d_ws + a_xb);

    hipMemsetAsync(ovf_count, 0, 4, stream);
    convA_kernel<<<NWG_A, A_THREADS, 0, stream>>>(x, xb, adj_vals, row, col,
                                                  coarse, lens, ovf_count, ovf);
    partB_kernel<<<NB, 1024, 0, stream>>>(coarse, lens, payload, cursor, ovf_count, ovf);
    gather_bf16_kernel<<<N_NODES / 8, 256, 0, stream>>>(xb, payload, cursor, out);
    ovf_pack_kernel<<<64, 256, 0, stream>>>(x, ovf_count, ovf, out);
  } else {
    hipMemsetAsync(d_out, 0, (size_t)out_size * sizeof(float), stream);
    long long total_threads = (long long)N_EDGES * 64;
    scatter_fused_kernel<<<(int)((total_threads + 255) / 256), 256, 0, stream>>>(
        x, adj_vals, row, col, out);
  }
}